// Round 32
// baseline (531.206 us; speedup 1.0000x reference)
//
#include <hip/hip_runtime.h>
#include <hip/hip_fp16.h>

#define NN 50000
#define TT 12
#define EE 800000
#define IN_C 32
#define HID 64
#define OUT_C 32
#define BSZ 64                        // nodes per bucket
#define NB ((NN + BSZ - 1) / BSZ)     // 782 buckets
#define EPB 8192                      // edges per bsort block (ent fits LDS)
#define ABLK ((EE + EPB - 1) / EPB)   // 98
#define BST 512                       // bsort threads (8 waves: occupancy)
#define GT 4                          // timesteps per gate block
#define XPAIRS ((size_t)TT * NN * 16) // half2 elements in x

typedef _Float16 half8_t __attribute__((ext_vector_type(8)));
typedef float f32x4_t __attribute__((ext_vector_type(4)));

// ---------------- precompute folded gate matrices ----------------
// Mz = Wz @ Lz_w[:64] (32x64), Bz = bz @ Lz_w[:64] + Lz_b (64); same for h.
__global__ __launch_bounds__(64) void prep_kernel(
    const float* __restrict__ Wz, const float* __restrict__ bz,
    const float* __restrict__ Lzw, const float* __restrict__ Lzb,
    const float* __restrict__ Wh, const float* __restrict__ bh,
    const float* __restrict__ Lhw, const float* __restrict__ Lhb,
    float* __restrict__ Mz, float* __restrict__ Bz,
    float* __restrict__ Mh, float* __restrict__ Bh) {
  const int j = threadIdx.x;
  const int i = blockIdx.x;
  const int h = blockIdx.y;
  const float* W  = h ? Wh  : Wz;
  const float* b  = h ? bh  : bz;
  const float* L  = h ? Lhw : Lzw;
  const float* Lb = h ? Lhb : Lzb;
  float* M = h ? Mh : Mz;
  float* B = h ? Bh : Bz;
  if (i < IN_C) {
    float v = 0.f;
    for (int k = 0; k < HID; ++k) v += W[i * HID + k] * L[k * HID + j];
    M[i * HID + j] = v;
  } else {
    float v = Lb[j];
    for (int k = 0; k < HID; ++k) v += b[k] * L[k * HID + j];
    B[j] = v;
  }
}

// pack M into MFMA B-operand fp16 layout: B16[(g*4+cc)*64 + lane][i] =
// M_g[k = 8*(lane>>4)+i][col = cc*16 + (lane&15)]
__global__ __launch_bounds__(64) void prep_b16_kernel(
    const float* __restrict__ Mz, const float* __restrict__ Mh,
    _Float16* __restrict__ B16) {
  int l = threadIdx.x;
  int cc = blockIdx.x;  // coltile 0..3
  int g = blockIdx.y;   // 0=z, 1=h
  const float* M = g ? Mh : Mz;
#pragma unroll
  for (int i = 0; i < 8; ++i) {
    int k = (l >> 4) * 8 + i;
    int col = cc * 16 + (l & 15);
    B16[(((size_t)g * 4 + cc) * 64 + l) * 8 + i] = (_Float16)M[k * HID + col];
  }
}

// x [T,N,32] fp32 -> fp16 pairs
__global__ __launch_bounds__(256) void xconv_kernel(const float* __restrict__ x,
                                                    __half2* __restrict__ xh) {
  size_t i = (size_t)blockIdx.x * 256 + threadIdx.x;
  if (i < XPAIRS) {
    float2 f = ((const float2*)x)[i];
    xh[i] = __floats2half2_rn(f.x, f.y);
  }
}

// bsort v4 (VALIDATED R30/R31): LDS-staged sort + sequential streamout at
// 512 threads. NT stores on the stream-out (read next kernel; 77 MB can't
// stay in L2 — avoid evicting useful lines).
__global__ __launch_bounds__(BST) void bsort_kernel(
    const int* __restrict__ ei, const float* __restrict__ ew,
    unsigned long long* __restrict__ bin2G, int* __restrict__ runoffG,
    int tbase) {
  __shared__ int hist[NB];
  __shared__ int rnk[NB];
  __shared__ int lbase[NB + 1];
  __shared__ unsigned long long sent[EPB];  // 64 KB sorted-entry buffer
  int tl = blockIdx.y;
  const int* src = ei + (size_t)(tbase + tl) * 2 * EE;
  const int* dst = src + EE;
  const float* w = ew + (size_t)(tbase + tl) * EE;
  int t = threadIdx.x;
  for (int i = t; i < NB; i += BST) { hist[i] = 0; rnk[i] = 0; }
  __syncthreads();
  int e0 = blockIdx.x * EPB;
  int cnt = min(EPB, EE - e0);
  for (int i = t; i < cnt; i += BST) atomicAdd(&hist[dst[e0 + i] >> 6], 1);
  __syncthreads();
  if (t == 0) {
    int run = 0;
    for (int b = 0; b < NB; ++b) { lbase[b] = run; run += hist[b]; }
    lbase[NB] = run;  // == cnt
  }
  __syncthreads();
  int* rof = runoffG + ((size_t)tl * ABLK + blockIdx.x) * (NB + 1);
  for (int b = t; b < NB + 1; b += BST) rof[b] = lbase[b];
  for (int i = t; i < cnt; i += BST) {
    int d = dst[e0 + i], s = src[e0 + i];
    int b = d >> 6;
    unsigned short hw = __half_as_ushort(__float2half_rn(w[e0 + i]));
    int pos = lbase[b] + atomicAdd(&rnk[b], 1);
    sent[pos] = (unsigned long long)((unsigned)s | ((unsigned)(d & 63) << 16)) |
                ((unsigned long long)hw << 32);
  }
  __syncthreads();
  unsigned long long* reg = bin2G + ((size_t)tl * ABLK + blockIdx.x) * EPB;
  for (int i = t; i < cnt; i += BST)
    __builtin_nontemporal_store(sent[i], &reg[i]);
}

// bscan v2 (VALIDATED R26): bucket totals from runoff diffs + 1024-wide scan.
__global__ __launch_bounds__(1024) void bscan_kernel(const int* __restrict__ runoffG,
                                                     int* __restrict__ bbaseA) {
  __shared__ int s[1024];
  int tl = blockIdx.x, t = threadIdx.x;
  const int* runoff = runoffG + (size_t)tl * ABLK * (NB + 1);
  int v = 0;
  if (t < NB) {
    for (int blk = 0; blk < ABLK; ++blk)
      v += runoff[blk * (NB + 1) + t + 1] - runoff[blk * (NB + 1) + t];
  }
  s[t] = v;
  __syncthreads();
  for (int o = 1; o < 1024; o <<= 1) {
    int u = (t >= o) ? s[t - o] : 0;
    __syncthreads();
    s[t] += u;
    __syncthreads();
  }
  if (t < NB) bbaseA[(size_t)tl * NB + t] = s[t] - v;  // exclusive
}

// sortdeg (VALIDATED R31): wsum+cnt pass and place pass in one block; the
// place pass re-reads the block's runs L1/L2-hot (bin2 reads stay CACHED).
// sbuf writes stay normal (L2 write-combining keeps their amp at 1).
__global__ __launch_bounds__(256) void sortdeg_kernel(
    const int* __restrict__ runoffG, const unsigned long long* __restrict__ bin2G,
    const int* __restrict__ bbaseA, float* __restrict__ dinvA,
    unsigned* __restrict__ sbufG, int* __restrict__ noffG) {
  __shared__ float wsum[BSZ];
  __shared__ int cnt[BSZ];
  __shared__ int plc[BSZ];
  __shared__ int loff[BSZ];
  int tl = blockIdx.y, b = blockIdx.x;
  int t = threadIdx.x;
  if (t < BSZ) { wsum[t] = 0.f; cnt[t] = 0; }
  __syncthreads();
  const int* runoff = runoffG + (size_t)tl * ABLK * (NB + 1);
  int g = t >> 5;      // lane-group 0..7
  int lane = t & 31;
  // pass 1: wsum + cnt over the bucket's runs
  for (int blk = g; blk < ABLK; blk += 8) {
    int r0 = runoff[blk * (NB + 1) + b];
    int r1 = runoff[blk * (NB + 1) + b + 1];
    const unsigned long long* reg = bin2G + ((size_t)tl * ABLK + blk) * EPB;
    for (int i = r0 + lane; i < r1; i += 32) {
      unsigned long long u = reg[i];
      int dl = (int)((u >> 16) & 63u);
      atomicAdd(&wsum[dl], __half2float(__ushort_as_half((unsigned short)(u >> 32))));
      atomicAdd(&cnt[dl], 1);
    }
  }
  __syncthreads();
  if (t == 0) {
    int run = 0;
#pragma unroll
    for (int i = 0; i < BSZ; ++i) { loff[i] = run; run += cnt[i]; }
  }
  __syncthreads();
  int base = bbaseA[(size_t)tl * NB + b];
  int* noff = noffG + (size_t)tl * (NN + 1);
  if (t < BSZ) {
    int n = b * BSZ + t;
    int v = base + loff[t];
    plc[t] = v;
    if (n < NN) {
      noff[n] = v;
      dinvA[(size_t)tl * NN + n] = rsqrtf(1.0f + wsum[t]);
    }
  }
  if (b == 0 && t == 0) noff[NN] = EE;
  __syncthreads();
  unsigned* sbuf = sbufG + (size_t)tl * EE;
  // pass 2: place {src16 | raw fp16 w << 16} (runs L1/L2-hot from pass 1)
  for (int blk = g; blk < ABLK; blk += 8) {
    int r0 = runoff[blk * (NB + 1) + b];
    int r1 = runoff[blk * (NB + 1) + b + 1];
    const unsigned long long* reg = bin2G + ((size_t)tl * ABLK + blk) * EPB;
    for (int i = r0 + lane; i < r1; i += 32) {
      unsigned long long u = reg[i];
      int pos = atomicAdd(&plc[(int)((u >> 16) & 63u)], 1);
      sbuf[pos] = (unsigned)(u & 0xFFFFu) | ((unsigned)(u >> 32) << 16);
    }
  }
}

// Pass B1 (VALIDATED R31 structure): pure gather; t-major grid. NT loads on
// sbuf (single-use stream) and NT stores on y (not re-read here) keep these
// 2x 3.2 MB/t streams OUT of L2 so xh_t (3.2 MB) stays resident — R31's
// FETCH was 193 MB vs ~82 compulsory from exactly this pollution.
__global__ __launch_bounds__(256) void gather_y_kernel(
    const __half2* __restrict__ xh,
    const float* __restrict__ dinvA, const int* __restrict__ noffG,
    const unsigned* __restrict__ sbufG, __half2* __restrict__ yG, int tbase) {
  int t = threadIdx.x;
  int w = t >> 6;            // wave 0..3
  int lane = t & 63;
  int h2 = lane >> 5;        // node half 0/1
  int g = (lane >> 2) & 7;   // edge group 0..7
  int cq = lane & 3;         // channel oct 0..3 (8 fp16 ch = uint4)
  int tl = blockIdx.y;
  int n = blockIdx.x * 8 + w * 2 + h2;  // NN % 8 == 0, no tail

  const float* dinv = dinvA + (size_t)tl * NN;
  const int* noff = noffG + (size_t)tl * (NN + 1);
  const unsigned* sbuf = sbufG + (size_t)tl * EE;
  const __half2* xht = xh + (size_t)(tbase + tl) * NN * 16;

  int e0 = noff[n], e1 = noff[n + 1];
  float v0 = 0.f, v1 = 0.f, v2 = 0.f, v3 = 0.f;
  float v4 = 0.f, v5 = 0.f, v6 = 0.f, v7 = 0.f;
  for (int e = e0 + g; e < e1; e += 8) {
    unsigned u = __builtin_nontemporal_load(&sbuf[e]);  // single-use stream
    int s = (int)(u & 0xFFFFu);
    float nm = __half2float(__ushort_as_half((unsigned short)(u >> 16))) * dinv[s];
    uint4 xr = ((const uint4*)(xht + (size_t)s * 16))[cq];  // CACHED (hot)
    const __half2* hp = (const __half2*)&xr;
    float2 f0 = __half22float2(hp[0]);
    float2 f1 = __half22float2(hp[1]);
    float2 f2 = __half22float2(hp[2]);
    float2 f3 = __half22float2(hp[3]);
    v0 += nm * f0.x; v1 += nm * f0.y;
    v2 += nm * f1.x; v3 += nm * f1.y;
    v4 += nm * f2.x; v5 += nm * f2.y;
    v6 += nm * f3.x; v7 += nm * f3.y;
  }
  // reduce over the 8 edge groups (lane bits 2,3,4 — stays in node half/oct)
#pragma unroll
  for (int m = 4; m <= 16; m <<= 1) {
    v0 += __shfl_xor(v0, m); v1 += __shfl_xor(v1, m);
    v2 += __shfl_xor(v2, m); v3 += __shfl_xor(v3, m);
    v4 += __shfl_xor(v4, m); v5 += __shfl_xor(v5, m);
    v6 += __shfl_xor(v6, m); v7 += __shfl_xor(v7, m);
  }
  if (g == 0) {  // 4 lanes per node x 8 ch = all 32 channels
    float dv = dinv[n];
    uint4 xs = ((const uint4*)(xht + (size_t)n * 16))[cq];  // fp16 self-loop
    const __half2* hs = (const __half2*)&xs;
    float2 s0 = __half22float2(hs[0]);
    float2 s1 = __half22float2(hs[1]);
    float2 s2 = __half22float2(hs[2]);
    float2 s3 = __half22float2(hs[3]);
    __half2 o[4];
    o[0] = __floats2half2_rn(dv * (v0 + dv * s0.x), dv * (v1 + dv * s0.y));
    o[1] = __floats2half2_rn(dv * (v2 + dv * s1.x), dv * (v3 + dv * s1.y));
    o[2] = __floats2half2_rn(dv * (v4 + dv * s2.x), dv * (v5 + dv * s2.y));
    o[3] = __floats2half2_rn(dv * (v6 + dv * s3.x), dv * (v7 + dv * s3.y));
    unsigned long long ov[2];
    __builtin_memcpy(ov, o, 16);
    unsigned long long* yp =
        (unsigned long long*)(yG + ((size_t)tl * NN + n) * 16 + cq * 4);
    __builtin_nontemporal_store(ov[0], yp);      // y not re-read this kernel
    __builtin_nontemporal_store(ov[1], yp + 1);
  }
}

// Pass B2: MFMA gate (proven R17..R31). NT loads on the y A-frags (each
// read exactly once across the whole launch).
__global__ __launch_bounds__(256) void gate_acc_kernel(
    const __half2* __restrict__ yG, const _Float16* __restrict__ B16,
    const float* __restrict__ Bz, const float* __restrict__ Bh,
    float* __restrict__ acc, int c) {
  int t = threadIdx.x;
  int w = t >> 6;
  int lane = t & 63;
  int nb = blockIdx.x * BSZ;
  int t0 = blockIdx.y * GT;
  int te = min(t0 + GT, c);

  half8_t bf[8];
#pragma unroll
  for (int q = 0; q < 8; ++q)
    bf[q] = *(const half8_t*)(B16 + ((size_t)q * 64 + lane) * 8);
  float bzv[4], bhv[4];
#pragma unroll
  for (int cc = 0; cc < 4; ++cc) {
    bzv[cc] = Bz[cc * 16 + (lane & 15)];
    bhv[cc] = Bh[cc * 16 + (lane & 15)];
  }
  float accr[16];
#pragma unroll
  for (int k = 0; k < 16; ++k) accr[k] = 0.f;

  const _Float16* yF = (const _Float16*)yG;
  int arow = nb + w * 16 + (lane & 15);   // A row this lane loads
  if (arow >= NN) arow = NN - 1;          // tail clamp (results discarded)
  int koff = (lane >> 4) * 8;             // k-offset within the row

  for (int tl = t0; tl < te; ++tl) {
    const unsigned long long* pa =
        (const unsigned long long*)(yF + ((size_t)tl * NN + arow) * 32 + koff);
    unsigned long long av[2];
    av[0] = __builtin_nontemporal_load(pa);
    av[1] = __builtin_nontemporal_load(pa + 1);
    half8_t a;
    __builtin_memcpy(&a, av, 16);
    f32x4_t dz0 = {0.f, 0.f, 0.f, 0.f};
    f32x4_t dz[4], dh[4];
#pragma unroll
    for (int cc = 0; cc < 4; ++cc) {
      dz[cc] = __builtin_amdgcn_mfma_f32_16x16x32_f16(a, bf[cc], dz0, 0, 0, 0);
      dh[cc] = __builtin_amdgcn_mfma_f32_16x16x32_f16(a, bf[4 + cc], dz0, 0, 0, 0);
    }
#pragma unroll
    for (int cc = 0; cc < 4; ++cc) {
#pragma unroll
      for (int r = 0; r < 4; ++r) {
        float za = dz[cc][r] + bzv[cc];
        float ha = dh[cc][r] + bhv[cc];
        float z = 1.0f / (1.0f + __expf(-za));
        float th = 1.0f - 2.0f / (__expf(2.f * ha) + 1.0f);
        accr[cc * 4 + r] += (1.0f - z) * th;
      }
    }
  }
#pragma unroll
  for (int cc = 0; cc < 4; ++cc) {
#pragma unroll
    for (int r = 0; r < 4; ++r) {
      int n = nb + w * 16 + (lane >> 4) * 4 + r;
      int j = cc * 16 + (lane & 15);
      if (n < NN) atomicAdd(&acc[(size_t)n * HID + j], accr[cc * 4 + r]);
    }
  }
}

// out[n][o] = (acc[n]/T) . W_out[:,o] + b_out[o]
__global__ __launch_bounds__(256) void out_kernel(const float* __restrict__ acc,
                                                  const float* __restrict__ W_out,
                                                  const float* __restrict__ b_out,
                                                  float* __restrict__ out) {
  __shared__ float sW[HID * OUT_C], sB[OUT_C];
  for (int i = threadIdx.x; i < HID * OUT_C; i += 256) sW[i] = W_out[i];
  if (threadIdx.x < OUT_C) sB[threadIdx.x] = b_out[threadIdx.x];
  __syncthreads();
  unsigned tid = blockIdx.x * 256u + threadIdx.x;
  unsigned n = tid >> 5;
  int o = tid & 31;
  if (n >= NN) return;
  const float* ar = acc + (size_t)n * HID;
  float v = 0.f;
#pragma unroll
  for (int k = 0; k < HID; ++k) v += ar[k] * sW[k * OUT_C + o];
  out[(size_t)n * OUT_C + o] = v * (1.0f / (float)TT) + sB[o];
}

static inline char* alignp(char* p, size_t a) {
  return (char*)(((size_t)p + a - 1) & ~(a - 1));
}

extern "C" void kernel_launch(void* const* d_in, const int* in_sizes, int n_in,
                              void* d_out, int out_size, void* d_ws, size_t ws_size,
                              hipStream_t stream) {
  const float* x     = (const float*)d_in[0];  // [T,N,32]
  const int*   ei    = (const int*)d_in[1];    // [T,2,E]
  const float* ew    = (const float*)d_in[2];  // [T,E]
  const float* Wz    = (const float*)d_in[3];
  const float* bz    = (const float*)d_in[4];
  // d_in[5..6] (Wr,br) dead: H==0 so R unused
  const float* Wh    = (const float*)d_in[7];
  const float* bh    = (const float*)d_in[8];
  const float* Lz_w  = (const float*)d_in[9];
  const float* Lz_b  = (const float*)d_in[10];
  // d_in[11..12] (Lr) dead
  const float* Lh_w  = (const float*)d_in[13];
  const float* Lh_b  = (const float*)d_in[14];
  const float* W_out = (const float*)d_in[15];
  const float* b_out = (const float*)d_in[16];
  float* out = (float*)d_out;

  // per-t sizes (bytes)
  const size_t noffB  = (size_t)(NN + 1) * 4;
  const size_t dinvB  = (size_t)NN * 4;
  const size_t bbB    = (size_t)NB * 4;
  const size_t rofB   = (size_t)ABLK * (NB + 1) * 4;      // 307 KB
  const size_t sbufB  = (size_t)EE * 4;                   // 3.2 MB
  const size_t bin2B  = (size_t)ABLK * EPB * 8;           // 6.42 MB (y aliases)
  const size_t perT   = noffB + dinvB + bbB + rofB + sbufB + bin2B;
  const size_t xhB    = XPAIRS * 4;                       // 38.4 MB
  const size_t fixedB = 4 * ((size_t)2 * IN_C * HID + 2 * HID)
                      + 8192 + (size_t)NN * HID * 4 + xhB + 4096;  // ~51.3 MB

  int nt = 12;
  if (ws_size < fixedB + 12 * perT) {
    nt = (int)((ws_size - fixedB) / perT);
    if (nt < 1) nt = 1;
    if (nt > 12) nt = 12;
  }

  char* p = (char*)d_ws;
  unsigned long long* bin2 = (unsigned long long*)p;  // 8-aligned at base
  p += bin2B * nt;
  int* noffG  = (int*)p;          p += noffB * nt;
  float* dinv = (float*)p;        p += dinvB * nt;
  int* bbase  = (int*)p;          p += bbB * nt;
  int* runoff = (int*)p;          p += rofB * nt;
  unsigned* sbufG = (unsigned*)p; p += sbufB * nt;
  p = alignp(p, 16);
  _Float16* B16 = (_Float16*)p;   p += 8192;  // 4096 fp16 MFMA B-frags
  float* Mz = (float*)p;
  float* Mh = Mz + IN_C * HID;
  float* Bz = Mh + IN_C * HID;
  float* Bh = Bz + HID;
  float* acc = Bh + HID;  // [N,64]
  p = alignp((char*)(acc + (size_t)NN * HID), 256);
  __half2* xh = (__half2*)p;
  // y [nt,N,32] fp16 aliases the bin2 region: bin2 is dead after sortdeg;
  // stream order guarantees sortdeg (reads bin2) < gather_y (writes y) <
  // gate_acc (reads y) < next chunk's bsort (rewrites bin2).
  __half2* yG = (__half2*)bin2;

  prep_kernel<<<dim3(IN_C + 1, 2), 64, 0, stream>>>(Wz, bz, Lz_w, Lz_b, Wh, bh,
                                                    Lh_w, Lh_b, Mz, Bz, Mh, Bh);
  prep_b16_kernel<<<dim3(4, 2), 64, 0, stream>>>(Mz, Mh, B16);
  xconv_kernel<<<(unsigned)((XPAIRS + 255) / 256), 256, 0, stream>>>(x, xh);
  hipMemsetAsync(acc, 0, (size_t)NN * HID * sizeof(float), stream);

  for (int tb = 0; tb < TT; tb += nt) {
    int c = (TT - tb < nt) ? (TT - tb) : nt;
    bsort_kernel<<<dim3(ABLK, c), BST, 0, stream>>>(ei, ew, bin2, runoff, tb);
    bscan_kernel<<<c, 1024, 0, stream>>>(runoff, bbase);
    sortdeg_kernel<<<dim3(NB, c), 256, 0, stream>>>(runoff, bin2, bbase,
                                                    dinv, sbufG, noffG);
    gather_y_kernel<<<dim3(NN / 8, c), 256, 0, stream>>>(xh, dinv, noffG,
                                                         sbufG, yG, tb);
    gate_acc_kernel<<<dim3(NB, (c + GT - 1) / GT), 256, 0, stream>>>(
        yG, B16, Bz, Bh, acc, c);
  }

  out_kernel<<<(NN * OUT_C + 255) / 256, 256, 0, stream>>>(acc, W_out, b_out, out);
}

// Round 33
// 493.974 us; speedup vs baseline: 1.0754x; 1.0754x over previous
//
#include <hip/hip_runtime.h>
#include <hip/hip_fp16.h>

#define NN 50000
#define TT 12
#define EE 800000
#define IN_C 32
#define HID 64
#define OUT_C 32
#define BSZ 64                        // nodes per bucket
#define NB ((NN + BSZ - 1) / BSZ)     // 782 buckets
#define EPB 8192                      // edges per bsort block (ent fits LDS)
#define ABLK ((EE + EPB - 1) / EPB)   // 98
#define BST 512                       // bsort threads (8 waves: occupancy)
#define GT 4                          // timesteps per gate block
#define XPAIRS ((size_t)TT * NN * 16) // half2 elements in x

typedef _Float16 half8_t __attribute__((ext_vector_type(8)));
typedef float f32x4_t __attribute__((ext_vector_type(4)));

// ---------------- precompute folded gate matrices ----------------
// Mz = Wz @ Lz_w[:64] (32x64), Bz = bz @ Lz_w[:64] + Lz_b (64); same for h.
__global__ __launch_bounds__(64) void prep_kernel(
    const float* __restrict__ Wz, const float* __restrict__ bz,
    const float* __restrict__ Lzw, const float* __restrict__ Lzb,
    const float* __restrict__ Wh, const float* __restrict__ bh,
    const float* __restrict__ Lhw, const float* __restrict__ Lhb,
    float* __restrict__ Mz, float* __restrict__ Bz,
    float* __restrict__ Mh, float* __restrict__ Bh) {
  const int j = threadIdx.x;
  const int i = blockIdx.x;
  const int h = blockIdx.y;
  const float* W  = h ? Wh  : Wz;
  const float* b  = h ? bh  : bz;
  const float* L  = h ? Lhw : Lzw;
  const float* Lb = h ? Lhb : Lzb;
  float* M = h ? Mh : Mz;
  float* B = h ? Bh : Bz;
  if (i < IN_C) {
    float v = 0.f;
    for (int k = 0; k < HID; ++k) v += W[i * HID + k] * L[k * HID + j];
    M[i * HID + j] = v;
  } else {
    float v = Lb[j];
    for (int k = 0; k < HID; ++k) v += b[k] * L[k * HID + j];
    B[j] = v;
  }
}

// pack M into MFMA B-operand fp16 layout: B16[(g*4+cc)*64 + lane][i] =
// M_g[k = 8*(lane>>4)+i][col = cc*16 + (lane&15)]
__global__ __launch_bounds__(64) void prep_b16_kernel(
    const float* __restrict__ Mz, const float* __restrict__ Mh,
    _Float16* __restrict__ B16) {
  int l = threadIdx.x;
  int cc = blockIdx.x;  // coltile 0..3
  int g = blockIdx.y;   // 0=z, 1=h
  const float* M = g ? Mh : Mz;
#pragma unroll
  for (int i = 0; i < 8; ++i) {
    int k = (l >> 4) * 8 + i;
    int col = cc * 16 + (l & 15);
    B16[(((size_t)g * 4 + cc) * 64 + l) * 8 + i] = (_Float16)M[k * HID + col];
  }
}

// x [T,N,32] fp32 -> fp16 pairs
__global__ __launch_bounds__(256) void xconv_kernel(const float* __restrict__ x,
                                                    __half2* __restrict__ xh) {
  size_t i = (size_t)blockIdx.x * 256 + threadIdx.x;
  if (i < XPAIRS) {
    float2 f = ((const float2*)x)[i];
    xh[i] = __floats2half2_rn(f.x, f.y);
  }
}

// bsort v4 (VALIDATED R30/R31): LDS-staged sort + sequential streamout at
// 512 threads. Coalesced reads, sequential writes: amp ~1.0 both sides.
__global__ __launch_bounds__(BST) void bsort_kernel(
    const int* __restrict__ ei, const float* __restrict__ ew,
    unsigned long long* __restrict__ bin2G, int* __restrict__ runoffG,
    int tbase) {
  __shared__ int hist[NB];
  __shared__ int rnk[NB];
  __shared__ int lbase[NB + 1];
  __shared__ unsigned long long sent[EPB];  // 64 KB sorted-entry buffer
  int tl = blockIdx.y;
  const int* src = ei + (size_t)(tbase + tl) * 2 * EE;
  const int* dst = src + EE;
  const float* w = ew + (size_t)(tbase + tl) * EE;
  int t = threadIdx.x;
  for (int i = t; i < NB; i += BST) { hist[i] = 0; rnk[i] = 0; }
  __syncthreads();
  int e0 = blockIdx.x * EPB;
  int cnt = min(EPB, EE - e0);
  for (int i = t; i < cnt; i += BST) atomicAdd(&hist[dst[e0 + i] >> 6], 1);
  __syncthreads();
  if (t == 0) {
    int run = 0;
    for (int b = 0; b < NB; ++b) { lbase[b] = run; run += hist[b]; }
    lbase[NB] = run;  // == cnt
  }
  __syncthreads();
  int* rof = runoffG + ((size_t)tl * ABLK + blockIdx.x) * (NB + 1);
  for (int b = t; b < NB + 1; b += BST) rof[b] = lbase[b];
  for (int i = t; i < cnt; i += BST) {
    int d = dst[e0 + i], s = src[e0 + i];
    int b = d >> 6;
    unsigned short hw = __half_as_ushort(__float2half_rn(w[e0 + i]));
    int pos = lbase[b] + atomicAdd(&rnk[b], 1);
    sent[pos] = (unsigned long long)((unsigned)s | ((unsigned)(d & 63) << 16)) |
                ((unsigned long long)hw << 32);
  }
  __syncthreads();
  unsigned long long* reg = bin2G + ((size_t)tl * ABLK + blockIdx.x) * EPB;
  for (int i = t; i < cnt; i += BST) reg[i] = sent[i];
}

// bscan v2 (VALIDATED R26): bucket totals from runoff diffs + 1024-wide scan.
__global__ __launch_bounds__(1024) void bscan_kernel(const int* __restrict__ runoffG,
                                                     int* __restrict__ bbaseA) {
  __shared__ int s[1024];
  int tl = blockIdx.x, t = threadIdx.x;
  const int* runoff = runoffG + (size_t)tl * ABLK * (NB + 1);
  int v = 0;
  if (t < NB) {
    for (int blk = 0; blk < ABLK; ++blk)
      v += runoff[blk * (NB + 1) + t + 1] - runoff[blk * (NB + 1) + t];
  }
  s[t] = v;
  __syncthreads();
  for (int o = 1; o < 1024; o <<= 1) {
    int u = (t >= o) ? s[t - o] : 0;
    __syncthreads();
    s[t] += u;
    __syncthreads();
  }
  if (t < NB) bbaseA[(size_t)tl * NB + t] = s[t] - v;  // exclusive
}

// sortdeg (VALIDATED R31): wsum+cnt pass and place pass in one block; the
// place pass re-reads the block's runs L1/L2-hot. sbuf stores RAW fp16 w;
// gather multiplies by dinv[src] (L2-resident table).
__global__ __launch_bounds__(256) void sortdeg_kernel(
    const int* __restrict__ runoffG, const unsigned long long* __restrict__ bin2G,
    const int* __restrict__ bbaseA, float* __restrict__ dinvA,
    unsigned* __restrict__ sbufG, int* __restrict__ noffG) {
  __shared__ float wsum[BSZ];
  __shared__ int cnt[BSZ];
  __shared__ int plc[BSZ];
  __shared__ int loff[BSZ];
  int tl = blockIdx.y, b = blockIdx.x;
  int t = threadIdx.x;
  if (t < BSZ) { wsum[t] = 0.f; cnt[t] = 0; }
  __syncthreads();
  const int* runoff = runoffG + (size_t)tl * ABLK * (NB + 1);
  int g = t >> 5;      // lane-group 0..7
  int lane = t & 31;
  // pass 1: wsum + cnt over the bucket's runs
  for (int blk = g; blk < ABLK; blk += 8) {
    int r0 = runoff[blk * (NB + 1) + b];
    int r1 = runoff[blk * (NB + 1) + b + 1];
    const unsigned long long* reg = bin2G + ((size_t)tl * ABLK + blk) * EPB;
    for (int i = r0 + lane; i < r1; i += 32) {
      unsigned long long u = reg[i];
      int dl = (int)((u >> 16) & 63u);
      atomicAdd(&wsum[dl], __half2float(__ushort_as_half((unsigned short)(u >> 32))));
      atomicAdd(&cnt[dl], 1);
    }
  }
  __syncthreads();
  if (t == 0) {
    int run = 0;
#pragma unroll
    for (int i = 0; i < BSZ; ++i) { loff[i] = run; run += cnt[i]; }
  }
  __syncthreads();
  int base = bbaseA[(size_t)tl * NB + b];
  int* noff = noffG + (size_t)tl * (NN + 1);
  if (t < BSZ) {
    int n = b * BSZ + t;
    int v = base + loff[t];
    plc[t] = v;
    if (n < NN) {
      noff[n] = v;
      dinvA[(size_t)tl * NN + n] = rsqrtf(1.0f + wsum[t]);
    }
  }
  if (b == 0 && t == 0) noff[NN] = EE;
  __syncthreads();
  unsigned* sbuf = sbufG + (size_t)tl * EE;
  // pass 2: place {src16 | raw fp16 w << 16} (runs L1/L2-hot from pass 1)
  for (int blk = g; blk < ABLK; blk += 8) {
    int r0 = runoff[blk * (NB + 1) + b];
    int r1 = runoff[blk * (NB + 1) + b + 1];
    const unsigned long long* reg = bin2G + ((size_t)tl * ABLK + blk) * EPB;
    for (int i = r0 + lane; i < r1; i += 32) {
      unsigned long long u = reg[i];
      int pos = atomicAdd(&plc[(int)((u >> 16) & 63u)], 1);
      sbuf[pos] = (unsigned)(u & 0xFFFFu) | ((unsigned)(u >> 32) << 16);
    }
  }
}

// Pass B1 (VALIDATED R31): pure gather; t-major grid keeps xh_t L2-resident;
// nm = w * dinv[src] computed here; fp16 self-loop from xh.
__global__ __launch_bounds__(256) void gather_y_kernel(
    const __half2* __restrict__ xh,
    const float* __restrict__ dinvA, const int* __restrict__ noffG,
    const unsigned* __restrict__ sbufG, __half2* __restrict__ yG, int tbase) {
  int t = threadIdx.x;
  int w = t >> 6;            // wave 0..3
  int lane = t & 63;
  int h2 = lane >> 5;        // node half 0/1
  int g = (lane >> 2) & 7;   // edge group 0..7
  int cq = lane & 3;         // channel oct 0..3 (8 fp16 ch = uint4)
  int tl = blockIdx.y;
  int n = blockIdx.x * 8 + w * 2 + h2;  // NN % 8 == 0, no tail

  const float* dinv = dinvA + (size_t)tl * NN;
  const int* noff = noffG + (size_t)tl * (NN + 1);
  const unsigned* sbuf = sbufG + (size_t)tl * EE;
  const __half2* xht = xh + (size_t)(tbase + tl) * NN * 16;

  int e0 = noff[n], e1 = noff[n + 1];
  float v0 = 0.f, v1 = 0.f, v2 = 0.f, v3 = 0.f;
  float v4 = 0.f, v5 = 0.f, v6 = 0.f, v7 = 0.f;
  for (int e = e0 + g; e < e1; e += 8) {
    unsigned u = sbuf[e];  // 4 lanes same addr: broadcast; intra-line reuse
    int s = (int)(u & 0xFFFFu);
    float nm = __half2float(__ushort_as_half((unsigned short)(u >> 16))) * dinv[s];
    uint4 xr = ((const uint4*)(xht + (size_t)s * 16))[cq];
    const __half2* hp = (const __half2*)&xr;
    float2 f0 = __half22float2(hp[0]);
    float2 f1 = __half22float2(hp[1]);
    float2 f2 = __half22float2(hp[2]);
    float2 f3 = __half22float2(hp[3]);
    v0 += nm * f0.x; v1 += nm * f0.y;
    v2 += nm * f1.x; v3 += nm * f1.y;
    v4 += nm * f2.x; v5 += nm * f2.y;
    v6 += nm * f3.x; v7 += nm * f3.y;
  }
  // reduce over the 8 edge groups (lane bits 2,3,4 — stays in node half/oct)
#pragma unroll
  for (int m = 4; m <= 16; m <<= 1) {
    v0 += __shfl_xor(v0, m); v1 += __shfl_xor(v1, m);
    v2 += __shfl_xor(v2, m); v3 += __shfl_xor(v3, m);
    v4 += __shfl_xor(v4, m); v5 += __shfl_xor(v5, m);
    v6 += __shfl_xor(v6, m); v7 += __shfl_xor(v7, m);
  }
  if (g == 0) {  // 4 lanes per node x 8 ch = all 32 channels
    float dv = dinv[n];
    uint4 xs = ((const uint4*)(xht + (size_t)n * 16))[cq];  // fp16 self-loop
    const __half2* hs = (const __half2*)&xs;
    float2 s0 = __half22float2(hs[0]);
    float2 s1 = __half22float2(hs[1]);
    float2 s2 = __half22float2(hs[2]);
    float2 s3 = __half22float2(hs[3]);
    __half2 o[4];
    o[0] = __floats2half2_rn(dv * (v0 + dv * s0.x), dv * (v1 + dv * s0.y));
    o[1] = __floats2half2_rn(dv * (v2 + dv * s1.x), dv * (v3 + dv * s1.y));
    o[2] = __floats2half2_rn(dv * (v4 + dv * s2.x), dv * (v5 + dv * s2.y));
    o[3] = __floats2half2_rn(dv * (v6 + dv * s3.x), dv * (v7 + dv * s3.y));
    __half2* yp = yG + ((size_t)tl * NN + n) * 16 + cq * 4;
    *(uint4*)yp = *(const uint4*)o;  // 16B store; 4 lanes fill the 64B row
  }
}

// Pass B2: MFMA gate (proven R17..R31). P[64x64] = Y[64x32] @ M[32x64]
// per (64-node tile, t) via 16x16x32_f16; B-frags prepacked, loaded once.
__global__ __launch_bounds__(256) void gate_acc_kernel(
    const __half2* __restrict__ yG, const _Float16* __restrict__ B16,
    const float* __restrict__ Bz, const float* __restrict__ Bh,
    float* __restrict__ acc, int c) {
  int t = threadIdx.x;
  int w = t >> 6;
  int lane = t & 63;
  int nb = blockIdx.x * BSZ;
  int t0 = blockIdx.y * GT;
  int te = min(t0 + GT, c);

  half8_t bf[8];
#pragma unroll
  for (int q = 0; q < 8; ++q)
    bf[q] = *(const half8_t*)(B16 + ((size_t)q * 64 + lane) * 8);
  float bzv[4], bhv[4];
#pragma unroll
  for (int cc = 0; cc < 4; ++cc) {
    bzv[cc] = Bz[cc * 16 + (lane & 15)];
    bhv[cc] = Bh[cc * 16 + (lane & 15)];
  }
  float accr[16];
#pragma unroll
  for (int k = 0; k < 16; ++k) accr[k] = 0.f;

  const _Float16* yF = (const _Float16*)yG;
  int arow = nb + w * 16 + (lane & 15);   // A row this lane loads
  if (arow >= NN) arow = NN - 1;          // tail clamp (results discarded)
  int koff = (lane >> 4) * 8;             // k-offset within the row

  for (int tl = t0; tl < te; ++tl) {
    half8_t a = *(const half8_t*)(yF + ((size_t)tl * NN + arow) * 32 + koff);
    f32x4_t dz0 = {0.f, 0.f, 0.f, 0.f};
    f32x4_t dz[4], dh[4];
#pragma unroll
    for (int cc = 0; cc < 4; ++cc) {
      dz[cc] = __builtin_amdgcn_mfma_f32_16x16x32_f16(a, bf[cc], dz0, 0, 0, 0);
      dh[cc] = __builtin_amdgcn_mfma_f32_16x16x32_f16(a, bf[4 + cc], dz0, 0, 0, 0);
    }
#pragma unroll
    for (int cc = 0; cc < 4; ++cc) {
#pragma unroll
      for (int r = 0; r < 4; ++r) {
        float za = dz[cc][r] + bzv[cc];
        float ha = dh[cc][r] + bhv[cc];
        float z = 1.0f / (1.0f + __expf(-za));
        float th = 1.0f - 2.0f / (__expf(2.f * ha) + 1.0f);
        accr[cc * 4 + r] += (1.0f - z) * th;
      }
    }
  }
#pragma unroll
  for (int cc = 0; cc < 4; ++cc) {
#pragma unroll
    for (int r = 0; r < 4; ++r) {
      int n = nb + w * 16 + (lane >> 4) * 4 + r;
      int j = cc * 16 + (lane & 15);
      if (n < NN) atomicAdd(&acc[(size_t)n * HID + j], accr[cc * 4 + r]);
    }
  }
}

// out[n][o] = (acc[n]/T) . W_out[:,o] + b_out[o]
__global__ __launch_bounds__(256) void out_kernel(const float* __restrict__ acc,
                                                  const float* __restrict__ W_out,
                                                  const float* __restrict__ b_out,
                                                  float* __restrict__ out) {
  __shared__ float sW[HID * OUT_C], sB[OUT_C];
  for (int i = threadIdx.x; i < HID * OUT_C; i += 256) sW[i] = W_out[i];
  if (threadIdx.x < OUT_C) sB[threadIdx.x] = b_out[threadIdx.x];
  __syncthreads();
  unsigned tid = blockIdx.x * 256u + threadIdx.x;
  unsigned n = tid >> 5;
  int o = tid & 31;
  if (n >= NN) return;
  const float* ar = acc + (size_t)n * HID;
  float v = 0.f;
#pragma unroll
  for (int k = 0; k < HID; ++k) v += ar[k] * sW[k * OUT_C + o];
  out[(size_t)n * OUT_C + o] = v * (1.0f / (float)TT) + sB[o];
}

static inline char* alignp(char* p, size_t a) {
  return (char*)(((size_t)p + a - 1) & ~(a - 1));
}

extern "C" void kernel_launch(void* const* d_in, const int* in_sizes, int n_in,
                              void* d_out, int out_size, void* d_ws, size_t ws_size,
                              hipStream_t stream) {
  const float* x     = (const float*)d_in[0];  // [T,N,32]
  const int*   ei    = (const int*)d_in[1];    // [T,2,E]
  const float* ew    = (const float*)d_in[2];  // [T,E]
  const float* Wz    = (const float*)d_in[3];
  const float* bz    = (const float*)d_in[4];
  // d_in[5..6] (Wr,br) dead: H==0 so R unused
  const float* Wh    = (const float*)d_in[7];
  const float* bh    = (const float*)d_in[8];
  const float* Lz_w  = (const float*)d_in[9];
  const float* Lz_b  = (const float*)d_in[10];
  // d_in[11..12] (Lr) dead
  const float* Lh_w  = (const float*)d_in[13];
  const float* Lh_b  = (const float*)d_in[14];
  const float* W_out = (const float*)d_in[15];
  const float* b_out = (const float*)d_in[16];
  float* out = (float*)d_out;

  // per-t sizes (bytes)
  const size_t noffB  = (size_t)(NN + 1) * 4;
  const size_t dinvB  = (size_t)NN * 4;
  const size_t bbB    = (size_t)NB * 4;
  const size_t rofB   = (size_t)ABLK * (NB + 1) * 4;      // 307 KB
  const size_t sbufB  = (size_t)EE * 4;                   // 3.2 MB
  const size_t bin2B  = (size_t)ABLK * EPB * 8;           // 6.42 MB (y aliases)
  const size_t perT   = noffB + dinvB + bbB + rofB + sbufB + bin2B;
  const size_t xhB    = XPAIRS * 4;                       // 38.4 MB
  const size_t fixedB = 4 * ((size_t)2 * IN_C * HID + 2 * HID)
                      + 8192 + (size_t)NN * HID * 4 + xhB + 4096;  // ~51.3 MB

  int nt = 12;
  if (ws_size < fixedB + 12 * perT) {
    nt = (int)((ws_size - fixedB) / perT);
    if (nt < 1) nt = 1;
    if (nt > 12) nt = 12;
  }

  char* p = (char*)d_ws;
  unsigned long long* bin2 = (unsigned long long*)p;  // 8-aligned at base
  p += bin2B * nt;
  int* noffG  = (int*)p;          p += noffB * nt;
  float* dinv = (float*)p;        p += dinvB * nt;
  int* bbase  = (int*)p;          p += bbB * nt;
  int* runoff = (int*)p;          p += rofB * nt;
  unsigned* sbufG = (unsigned*)p; p += sbufB * nt;
  p = alignp(p, 16);
  _Float16* B16 = (_Float16*)p;   p += 8192;  // 4096 fp16 MFMA B-frags
  float* Mz = (float*)p;
  float* Mh = Mz + IN_C * HID;
  float* Bz = Mh + IN_C * HID;
  float* Bh = Bz + HID;
  float* acc = Bh + HID;  // [N,64]
  p = alignp((char*)(acc + (size_t)NN * HID), 256);
  __half2* xh = (__half2*)p;
  // y [nt,N,32] fp16 aliases the bin2 region: bin2 is dead after sortdeg;
  // stream order guarantees sortdeg (reads bin2) < gather_y (writes y) <
  // gate_acc (reads y) < next chunk's bsort (rewrites bin2).
  __half2* yG = (__half2*)bin2;

  prep_kernel<<<dim3(IN_C + 1, 2), 64, 0, stream>>>(Wz, bz, Lz_w, Lz_b, Wh, bh,
                                                    Lh_w, Lh_b, Mz, Bz, Mh, Bh);
  prep_b16_kernel<<<dim3(4, 2), 64, 0, stream>>>(Mz, Mh, B16);
  xconv_kernel<<<(unsigned)((XPAIRS + 255) / 256), 256, 0, stream>>>(x, xh);
  hipMemsetAsync(acc, 0, (size_t)NN * HID * sizeof(float), stream);

  for (int tb = 0; tb < TT; tb += nt) {
    int c = (TT - tb < nt) ? (TT - tb) : nt;
    bsort_kernel<<<dim3(ABLK, c), BST, 0, stream>>>(ei, ew, bin2, runoff, tb);
    bscan_kernel<<<c, 1024, 0, stream>>>(runoff, bbase);
    sortdeg_kernel<<<dim3(NB, c), 256, 0, stream>>>(runoff, bin2, bbase,
                                                    dinv, sbufG, noffG);
    gather_y_kernel<<<dim3(NN / 8, c), 256, 0, stream>>>(xh, dinv, noffG,
                                                         sbufG, yG, tb);
    gate_acc_kernel<<<dim3(NB, (c + GT - 1) / GT), 256, 0, stream>>>(
        yG, B16, Bz, Bh, acc, c);
  }

  out_kernel<<<(NN * OUT_C + 255) / 256, 256, 0, stream>>>(acc, W_out, b_out, out);
}

// Round 34
// 471.973 us; speedup vs baseline: 1.1255x; 1.0466x over previous
//
#include <hip/hip_runtime.h>
#include <hip/hip_fp16.h>

#define NN 50000
#define TT 12
#define EE 800000
#define IN_C 32
#define HID 64
#define OUT_C 32
#define BSZ 64                        // nodes per bucket
#define NB ((NN + BSZ - 1) / BSZ)     // 782 buckets
#define EPB 8192                      // edges per bsort block (ent fits LDS)
#define ABLK ((EE + EPB - 1) / EPB)   // 98
#define BST 512                       // bsort threads (8 waves: occupancy)
#define GT 4                          // timesteps per gate block
#define XPAIRS ((size_t)TT * NN * 16) // half2 elements in x

typedef _Float16 half8_t __attribute__((ext_vector_type(8)));
typedef float f32x4_t __attribute__((ext_vector_type(4)));

// ---------------- precompute folded gate matrices ----------------
// Mz = Wz @ Lz_w[:64] (32x64), Bz = bz @ Lz_w[:64] + Lz_b (64); same for h.
__global__ __launch_bounds__(64) void prep_kernel(
    const float* __restrict__ Wz, const float* __restrict__ bz,
    const float* __restrict__ Lzw, const float* __restrict__ Lzb,
    const float* __restrict__ Wh, const float* __restrict__ bh,
    const float* __restrict__ Lhw, const float* __restrict__ Lhb,
    float* __restrict__ Mz, float* __restrict__ Bz,
    float* __restrict__ Mh, float* __restrict__ Bh) {
  const int j = threadIdx.x;
  const int i = blockIdx.x;
  const int h = blockIdx.y;
  const float* W  = h ? Wh  : Wz;
  const float* b  = h ? bh  : bz;
  const float* L  = h ? Lhw : Lzw;
  const float* Lb = h ? Lhb : Lzb;
  float* M = h ? Mh : Mz;
  float* B = h ? Bh : Bz;
  if (i < IN_C) {
    float v = 0.f;
    for (int k = 0; k < HID; ++k) v += W[i * HID + k] * L[k * HID + j];
    M[i * HID + j] = v;
  } else {
    float v = Lb[j];
    for (int k = 0; k < HID; ++k) v += b[k] * L[k * HID + j];
    B[j] = v;
  }
}

// pack M into MFMA B-operand fp16 layout: B16[(g*4+cc)*64 + lane][i] =
// M_g[k = 8*(lane>>4)+i][col = cc*16 + (lane&15)]
__global__ __launch_bounds__(64) void prep_b16_kernel(
    const float* __restrict__ Mz, const float* __restrict__ Mh,
    _Float16* __restrict__ B16) {
  int l = threadIdx.x;
  int cc = blockIdx.x;  // coltile 0..3
  int g = blockIdx.y;   // 0=z, 1=h
  const float* M = g ? Mh : Mz;
#pragma unroll
  for (int i = 0; i < 8; ++i) {
    int k = (l >> 4) * 8 + i;
    int col = cc * 16 + (l & 15);
    B16[(((size_t)g * 4 + cc) * 64 + l) * 8 + i] = (_Float16)M[k * HID + col];
  }
}

// x [T,N,32] fp32 -> fp16 pairs
__global__ __launch_bounds__(256) void xconv_kernel(const float* __restrict__ x,
                                                    __half2* __restrict__ xh) {
  size_t i = (size_t)blockIdx.x * 256 + threadIdx.x;
  if (i < XPAIRS) {
    float2 f = ((const float2*)x)[i];
    xh[i] = __floats2half2_rn(f.x, f.y);
  }
}

// bsort v4 (VALIDATED R30/R31/R33): LDS-staged sort + sequential streamout
// at 512 threads. Coalesced reads, sequential writes: amp ~1.0 both sides.
__global__ __launch_bounds__(BST) void bsort_kernel(
    const int* __restrict__ ei, const float* __restrict__ ew,
    unsigned long long* __restrict__ bin2G, int* __restrict__ runoffG,
    int tbase) {
  __shared__ int hist[NB];
  __shared__ int rnk[NB];
  __shared__ int lbase[NB + 1];
  __shared__ unsigned long long sent[EPB];  // 64 KB sorted-entry buffer
  int tl = blockIdx.y;
  const int* src = ei + (size_t)(tbase + tl) * 2 * EE;
  const int* dst = src + EE;
  const float* w = ew + (size_t)(tbase + tl) * EE;
  int t = threadIdx.x;
  for (int i = t; i < NB; i += BST) { hist[i] = 0; rnk[i] = 0; }
  __syncthreads();
  int e0 = blockIdx.x * EPB;
  int cnt = min(EPB, EE - e0);
  for (int i = t; i < cnt; i += BST) atomicAdd(&hist[dst[e0 + i] >> 6], 1);
  __syncthreads();
  if (t == 0) {
    int run = 0;
    for (int b = 0; b < NB; ++b) { lbase[b] = run; run += hist[b]; }
    lbase[NB] = run;  // == cnt
  }
  __syncthreads();
  int* rof = runoffG + ((size_t)tl * ABLK + blockIdx.x) * (NB + 1);
  for (int b = t; b < NB + 1; b += BST) rof[b] = lbase[b];
  for (int i = t; i < cnt; i += BST) {
    int d = dst[e0 + i], s = src[e0 + i];
    int b = d >> 6;
    unsigned short hw = __half_as_ushort(__float2half_rn(w[e0 + i]));
    int pos = lbase[b] + atomicAdd(&rnk[b], 1);
    sent[pos] = (unsigned long long)((unsigned)s | ((unsigned)(d & 63) << 16)) |
                ((unsigned long long)hw << 32);
  }
  __syncthreads();
  unsigned long long* reg = bin2G + ((size_t)tl * ABLK + blockIdx.x) * EPB;
  for (int i = t; i < cnt; i += BST) reg[i] = sent[i];
}

// bscan v2 (VALIDATED R26): bucket totals from runoff diffs + 1024-wide scan.
__global__ __launch_bounds__(1024) void bscan_kernel(const int* __restrict__ runoffG,
                                                     int* __restrict__ bbaseA) {
  __shared__ int s[1024];
  int tl = blockIdx.x, t = threadIdx.x;
  const int* runoff = runoffG + (size_t)tl * ABLK * (NB + 1);
  int v = 0;
  if (t < NB) {
    for (int blk = 0; blk < ABLK; ++blk)
      v += runoff[blk * (NB + 1) + t + 1] - runoff[blk * (NB + 1) + t];
  }
  s[t] = v;
  __syncthreads();
  for (int o = 1; o < 1024; o <<= 1) {
    int u = (t >= o) ? s[t - o] : 0;
    __syncthreads();
    s[t] += u;
    __syncthreads();
  }
  if (t < NB) bbaseA[(size_t)tl * NB + t] = s[t] - v;  // exclusive
}

// sortdeg v2: R31-validated merge, regrouped to 16 LANE-GROUPS OF 16 (was
// 8x32). Bucket runs average 10.5 edges, so 32-lane groups idled 2/3 of
// their lanes and each group walked ~12 runs serially; 16x16 doubles
// run-parallelism and halves idle lanes. Semantics identical (LDS claim
// order only — the validated determinism class).
__global__ __launch_bounds__(256) void sortdeg_kernel(
    const int* __restrict__ runoffG, const unsigned long long* __restrict__ bin2G,
    const int* __restrict__ bbaseA, float* __restrict__ dinvA,
    unsigned* __restrict__ sbufG, int* __restrict__ noffG) {
  __shared__ float wsum[BSZ];
  __shared__ int cnt[BSZ];
  __shared__ int plc[BSZ];
  __shared__ int loff[BSZ];
  int tl = blockIdx.y, b = blockIdx.x;
  int t = threadIdx.x;
  if (t < BSZ) { wsum[t] = 0.f; cnt[t] = 0; }
  __syncthreads();
  const int* runoff = runoffG + (size_t)tl * ABLK * (NB + 1);
  int g = t >> 4;      // lane-group 0..15
  int lane = t & 15;
  // pass 1: wsum + cnt over the bucket's runs
  for (int blk = g; blk < ABLK; blk += 16) {
    int r0 = runoff[blk * (NB + 1) + b];
    int r1 = runoff[blk * (NB + 1) + b + 1];
    const unsigned long long* reg = bin2G + ((size_t)tl * ABLK + blk) * EPB;
    for (int i = r0 + lane; i < r1; i += 16) {
      unsigned long long u = reg[i];
      int dl = (int)((u >> 16) & 63u);
      atomicAdd(&wsum[dl], __half2float(__ushort_as_half((unsigned short)(u >> 32))));
      atomicAdd(&cnt[dl], 1);
    }
  }
  __syncthreads();
  if (t == 0) {
    int run = 0;
#pragma unroll
    for (int i = 0; i < BSZ; ++i) { loff[i] = run; run += cnt[i]; }
  }
  __syncthreads();
  int base = bbaseA[(size_t)tl * NB + b];
  int* noff = noffG + (size_t)tl * (NN + 1);
  if (t < BSZ) {
    int n = b * BSZ + t;
    int v = base + loff[t];
    plc[t] = v;
    if (n < NN) {
      noff[n] = v;
      dinvA[(size_t)tl * NN + n] = rsqrtf(1.0f + wsum[t]);
    }
  }
  if (b == 0 && t == 0) noff[NN] = EE;
  __syncthreads();
  unsigned* sbuf = sbufG + (size_t)tl * EE;
  // pass 2: place {src16 | raw fp16 w << 16} (runs L1/L2-hot from pass 1)
  for (int blk = g; blk < ABLK; blk += 16) {
    int r0 = runoff[blk * (NB + 1) + b];
    int r1 = runoff[blk * (NB + 1) + b + 1];
    const unsigned long long* reg = bin2G + ((size_t)tl * ABLK + blk) * EPB;
    for (int i = r0 + lane; i < r1; i += 16) {
      unsigned long long u = reg[i];
      int pos = atomicAdd(&plc[(int)((u >> 16) & 63u)], 1);
      sbuf[pos] = (unsigned)(u & 0xFFFFu) | ((unsigned)(u >> 32) << 16);
    }
  }
}

// Pass B1 (VALIDATED R31/R33): pure gather; t-major grid keeps xh_t
// L2-resident; nm = w * dinv[src] computed here; fp16 self-loop from xh.
__global__ __launch_bounds__(256) void gather_y_kernel(
    const __half2* __restrict__ xh,
    const float* __restrict__ dinvA, const int* __restrict__ noffG,
    const unsigned* __restrict__ sbufG, __half2* __restrict__ yG, int tbase) {
  int t = threadIdx.x;
  int w = t >> 6;            // wave 0..3
  int lane = t & 63;
  int h2 = lane >> 5;        // node half 0/1
  int g = (lane >> 2) & 7;   // edge group 0..7
  int cq = lane & 3;         // channel oct 0..3 (8 fp16 ch = uint4)
  int tl = blockIdx.y;
  int n = blockIdx.x * 8 + w * 2 + h2;  // NN % 8 == 0, no tail

  const float* dinv = dinvA + (size_t)tl * NN;
  const int* noff = noffG + (size_t)tl * (NN + 1);
  const unsigned* sbuf = sbufG + (size_t)tl * EE;
  const __half2* xht = xh + (size_t)(tbase + tl) * NN * 16;

  int e0 = noff[n], e1 = noff[n + 1];
  float v0 = 0.f, v1 = 0.f, v2 = 0.f, v3 = 0.f;
  float v4 = 0.f, v5 = 0.f, v6 = 0.f, v7 = 0.f;
  for (int e = e0 + g; e < e1; e += 8) {
    unsigned u = sbuf[e];  // 4 lanes same addr: broadcast; intra-line reuse
    int s = (int)(u & 0xFFFFu);
    float nm = __half2float(__ushort_as_half((unsigned short)(u >> 16))) * dinv[s];
    uint4 xr = ((const uint4*)(xht + (size_t)s * 16))[cq];
    const __half2* hp = (const __half2*)&xr;
    float2 f0 = __half22float2(hp[0]);
    float2 f1 = __half22float2(hp[1]);
    float2 f2 = __half22float2(hp[2]);
    float2 f3 = __half22float2(hp[3]);
    v0 += nm * f0.x; v1 += nm * f0.y;
    v2 += nm * f1.x; v3 += nm * f1.y;
    v4 += nm * f2.x; v5 += nm * f2.y;
    v6 += nm * f3.x; v7 += nm * f3.y;
  }
  // reduce over the 8 edge groups (lane bits 2,3,4 — stays in node half/oct)
#pragma unroll
  for (int m = 4; m <= 16; m <<= 1) {
    v0 += __shfl_xor(v0, m); v1 += __shfl_xor(v1, m);
    v2 += __shfl_xor(v2, m); v3 += __shfl_xor(v3, m);
    v4 += __shfl_xor(v4, m); v5 += __shfl_xor(v5, m);
    v6 += __shfl_xor(v6, m); v7 += __shfl_xor(v7, m);
  }
  if (g == 0) {  // 4 lanes per node x 8 ch = all 32 channels
    float dv = dinv[n];
    uint4 xs = ((const uint4*)(xht + (size_t)n * 16))[cq];  // fp16 self-loop
    const __half2* hs = (const __half2*)&xs;
    float2 s0 = __half22float2(hs[0]);
    float2 s1 = __half22float2(hs[1]);
    float2 s2 = __half22float2(hs[2]);
    float2 s3 = __half22float2(hs[3]);
    __half2 o[4];
    o[0] = __floats2half2_rn(dv * (v0 + dv * s0.x), dv * (v1 + dv * s0.y));
    o[1] = __floats2half2_rn(dv * (v2 + dv * s1.x), dv * (v3 + dv * s1.y));
    o[2] = __floats2half2_rn(dv * (v4 + dv * s2.x), dv * (v5 + dv * s2.y));
    o[3] = __floats2half2_rn(dv * (v6 + dv * s3.x), dv * (v7 + dv * s3.y));
    __half2* yp = yG + ((size_t)tl * NN + n) * 16 + cq * 4;
    *(uint4*)yp = *(const uint4*)o;  // 16B store; 4 lanes fill the 64B row
  }
}

// Pass B2: MFMA gate (proven R17..R33). P[64x64] = Y[64x32] @ M[32x64]
// per (64-node tile, t) via 16x16x32_f16; B-frags prepacked, loaded once.
__global__ __launch_bounds__(256) void gate_acc_kernel(
    const __half2* __restrict__ yG, const _Float16* __restrict__ B16,
    const float* __restrict__ Bz, const float* __restrict__ Bh,
    float* __restrict__ acc, int c) {
  int t = threadIdx.x;
  int w = t >> 6;
  int lane = t & 63;
  int nb = blockIdx.x * BSZ;
  int t0 = blockIdx.y * GT;
  int te = min(t0 + GT, c);

  half8_t bf[8];
#pragma unroll
  for (int q = 0; q < 8; ++q)
    bf[q] = *(const half8_t*)(B16 + ((size_t)q * 64 + lane) * 8);
  float bzv[4], bhv[4];
#pragma unroll
  for (int cc = 0; cc < 4; ++cc) {
    bzv[cc] = Bz[cc * 16 + (lane & 15)];
    bhv[cc] = Bh[cc * 16 + (lane & 15)];
  }
  float accr[16];
#pragma unroll
  for (int k = 0; k < 16; ++k) accr[k] = 0.f;

  const _Float16* yF = (const _Float16*)yG;
  int arow = nb + w * 16 + (lane & 15);   // A row this lane loads
  if (arow >= NN) arow = NN - 1;          // tail clamp (results discarded)
  int koff = (lane >> 4) * 8;             // k-offset within the row

  for (int tl = t0; tl < te; ++tl) {
    half8_t a = *(const half8_t*)(yF + ((size_t)tl * NN + arow) * 32 + koff);
    f32x4_t dz0 = {0.f, 0.f, 0.f, 0.f};
    f32x4_t dz[4], dh[4];
#pragma unroll
    for (int cc = 0; cc < 4; ++cc) {
      dz[cc] = __builtin_amdgcn_mfma_f32_16x16x32_f16(a, bf[cc], dz0, 0, 0, 0);
      dh[cc] = __builtin_amdgcn_mfma_f32_16x16x32_f16(a, bf[4 + cc], dz0, 0, 0, 0);
    }
#pragma unroll
    for (int cc = 0; cc < 4; ++cc) {
#pragma unroll
      for (int r = 0; r < 4; ++r) {
        float za = dz[cc][r] + bzv[cc];
        float ha = dh[cc][r] + bhv[cc];
        float z = 1.0f / (1.0f + __expf(-za));
        float th = 1.0f - 2.0f / (__expf(2.f * ha) + 1.0f);
        accr[cc * 4 + r] += (1.0f - z) * th;
      }
    }
  }
#pragma unroll
  for (int cc = 0; cc < 4; ++cc) {
#pragma unroll
    for (int r = 0; r < 4; ++r) {
      int n = nb + w * 16 + (lane >> 4) * 4 + r;
      int j = cc * 16 + (lane & 15);
      if (n < NN) atomicAdd(&acc[(size_t)n * HID + j], accr[cc * 4 + r]);
    }
  }
}

// out[n][o] = (acc[n]/T) . W_out[:,o] + b_out[o]
__global__ __launch_bounds__(256) void out_kernel(const float* __restrict__ acc,
                                                  const float* __restrict__ W_out,
                                                  const float* __restrict__ b_out,
                                                  float* __restrict__ out) {
  __shared__ float sW[HID * OUT_C], sB[OUT_C];
  for (int i = threadIdx.x; i < HID * OUT_C; i += 256) sW[i] = W_out[i];
  if (threadIdx.x < OUT_C) sB[threadIdx.x] = b_out[threadIdx.x];
  __syncthreads();
  unsigned tid = blockIdx.x * 256u + threadIdx.x;
  unsigned n = tid >> 5;
  int o = tid & 31;
  if (n >= NN) return;
  const float* ar = acc + (size_t)n * HID;
  float v = 0.f;
#pragma unroll
  for (int k = 0; k < HID; ++k) v += ar[k] * sW[k * OUT_C + o];
  out[(size_t)n * OUT_C + o] = v * (1.0f / (float)TT) + sB[o];
}

static inline char* alignp(char* p, size_t a) {
  return (char*)(((size_t)p + a - 1) & ~(a - 1));
}

extern "C" void kernel_launch(void* const* d_in, const int* in_sizes, int n_in,
                              void* d_out, int out_size, void* d_ws, size_t ws_size,
                              hipStream_t stream) {
  const float* x     = (const float*)d_in[0];  // [T,N,32]
  const int*   ei    = (const int*)d_in[1];    // [T,2,E]
  const float* ew    = (const float*)d_in[2];  // [T,E]
  const float* Wz    = (const float*)d_in[3];
  const float* bz    = (const float*)d_in[4];
  // d_in[5..6] (Wr,br) dead: H==0 so R unused
  const float* Wh    = (const float*)d_in[7];
  const float* bh    = (const float*)d_in[8];
  const float* Lz_w  = (const float*)d_in[9];
  const float* Lz_b  = (const float*)d_in[10];
  // d_in[11..12] (Lr) dead
  const float* Lh_w  = (const float*)d_in[13];
  const float* Lh_b  = (const float*)d_in[14];
  const float* W_out = (const float*)d_in[15];
  const float* b_out = (const float*)d_in[16];
  float* out = (float*)d_out;

  // per-t sizes (bytes)
  const size_t noffB  = (size_t)(NN + 1) * 4;
  const size_t dinvB  = (size_t)NN * 4;
  const size_t bbB    = (size_t)NB * 4;
  const size_t rofB   = (size_t)ABLK * (NB + 1) * 4;      // 307 KB
  const size_t sbufB  = (size_t)EE * 4;                   // 3.2 MB
  const size_t bin2B  = (size_t)ABLK * EPB * 8;           // 6.42 MB (y aliases)
  const size_t perT   = noffB + dinvB + bbB + rofB + sbufB + bin2B;
  const size_t xhB    = XPAIRS * 4;                       // 38.4 MB
  const size_t fixedB = 4 * ((size_t)2 * IN_C * HID + 2 * HID)
                      + 8192 + (size_t)NN * HID * 4 + xhB + 4096;  // ~51.3 MB

  int nt = 12;
  if (ws_size < fixedB + 12 * perT) {
    nt = (int)((ws_size - fixedB) / perT);
    if (nt < 1) nt = 1;
    if (nt > 12) nt = 12;
  }

  char* p = (char*)d_ws;
  unsigned long long* bin2 = (unsigned long long*)p;  // 8-aligned at base
  p += bin2B * nt;
  int* noffG  = (int*)p;          p += noffB * nt;
  float* dinv = (float*)p;        p += dinvB * nt;
  int* bbase  = (int*)p;          p += bbB * nt;
  int* runoff = (int*)p;          p += rofB * nt;
  unsigned* sbufG = (unsigned*)p; p += sbufB * nt;
  p = alignp(p, 16);
  _Float16* B16 = (_Float16*)p;   p += 8192;  // 4096 fp16 MFMA B-frags
  float* Mz = (float*)p;
  float* Mh = Mz + IN_C * HID;
  float* Bz = Mh + IN_C * HID;
  float* Bh = Bz + HID;
  float* acc = Bh + HID;  // [N,64]
  p = alignp((char*)(acc + (size_t)NN * HID), 256);
  __half2* xh = (__half2*)p;
  // y [nt,N,32] fp16 aliases the bin2 region: bin2 is dead after sortdeg;
  // stream order guarantees sortdeg (reads bin2) < gather_y (writes y) <
  // gate_acc (reads y) < next chunk's bsort (rewrites bin2).
  __half2* yG = (__half2*)bin2;

  prep_kernel<<<dim3(IN_C + 1, 2), 64, 0, stream>>>(Wz, bz, Lz_w, Lz_b, Wh, bh,
                                                    Lh_w, Lh_b, Mz, Bz, Mh, Bh);
  prep_b16_kernel<<<dim3(4, 2), 64, 0, stream>>>(Mz, Mh, B16);
  xconv_kernel<<<(unsigned)((XPAIRS + 255) / 256), 256, 0, stream>>>(x, xh);
  hipMemsetAsync(acc, 0, (size_t)NN * HID * sizeof(float), stream);

  for (int tb = 0; tb < TT; tb += nt) {
    int c = (TT - tb < nt) ? (TT - tb) : nt;
    bsort_kernel<<<dim3(ABLK, c), BST, 0, stream>>>(ei, ew, bin2, runoff, tb);
    bscan_kernel<<<c, 1024, 0, stream>>>(runoff, bbase);
    sortdeg_kernel<<<dim3(NB, c), 256, 0, stream>>>(runoff, bin2, bbase,
                                                    dinv, sbufG, noffG);
    gather_y_kernel<<<dim3(NN / 8, c), 256, 0, stream>>>(xh, dinv, noffG,
                                                         sbufG, yG, tb);
    gate_acc_kernel<<<dim3(NB, (c + GT - 1) / GT), 256, 0, stream>>>(
        yG, B16, Bz, Bh, acc, c);
  }

  out_kernel<<<(NN * OUT_C + 255) / 256, 256, 0, stream>>>(acc, W_out, b_out, out);
}

// Round 35
// 469.265 us; speedup vs baseline: 1.1320x; 1.0058x over previous
//
#include <hip/hip_runtime.h>
#include <hip/hip_fp16.h>

#define NN 50000
#define TT 12
#define EE 800000
#define IN_C 32
#define HID 64
#define OUT_C 32
#define BSZ 64                        // nodes per bucket
#define NB ((NN + BSZ - 1) / BSZ)     // 782 buckets
#define EPB 8192                      // edges per bsort block (ent fits LDS)
#define ABLK ((EE + EPB - 1) / EPB)   // 98
#define BST 512                       // bsort threads (8 waves: occupancy)
#define GT 4                          // timesteps per gate block
#define XPAIRS ((size_t)TT * NN * 16) // half2 elements in x

typedef _Float16 half8_t __attribute__((ext_vector_type(8)));
typedef float f32x4_t __attribute__((ext_vector_type(4)));

// ---------------- precompute folded gate matrices ----------------
// Mz = Wz @ Lz_w[:64] (32x64), Bz = bz @ Lz_w[:64] + Lz_b (64); same for h.
__global__ __launch_bounds__(64) void prep_kernel(
    const float* __restrict__ Wz, const float* __restrict__ bz,
    const float* __restrict__ Lzw, const float* __restrict__ Lzb,
    const float* __restrict__ Wh, const float* __restrict__ bh,
    const float* __restrict__ Lhw, const float* __restrict__ Lhb,
    float* __restrict__ Mz, float* __restrict__ Bz,
    float* __restrict__ Mh, float* __restrict__ Bh) {
  const int j = threadIdx.x;
  const int i = blockIdx.x;
  const int h = blockIdx.y;
  const float* W  = h ? Wh  : Wz;
  const float* b  = h ? bh  : bz;
  const float* L  = h ? Lhw : Lzw;
  const float* Lb = h ? Lhb : Lzb;
  float* M = h ? Mh : Mz;
  float* B = h ? Bh : Bz;
  if (i < IN_C) {
    float v = 0.f;
    for (int k = 0; k < HID; ++k) v += W[i * HID + k] * L[k * HID + j];
    M[i * HID + j] = v;
  } else {
    float v = Lb[j];
    for (int k = 0; k < HID; ++k) v += b[k] * L[k * HID + j];
    B[j] = v;
  }
}

// pack M into MFMA B-operand fp16 layout: B16[(g*4+cc)*64 + lane][i] =
// M_g[k = 8*(lane>>4)+i][col = cc*16 + (lane&15)]
__global__ __launch_bounds__(64) void prep_b16_kernel(
    const float* __restrict__ Mz, const float* __restrict__ Mh,
    _Float16* __restrict__ B16) {
  int l = threadIdx.x;
  int cc = blockIdx.x;  // coltile 0..3
  int g = blockIdx.y;   // 0=z, 1=h
  const float* M = g ? Mh : Mz;
#pragma unroll
  for (int i = 0; i < 8; ++i) {
    int k = (l >> 4) * 8 + i;
    int col = cc * 16 + (l & 15);
    B16[(((size_t)g * 4 + cc) * 64 + l) * 8 + i] = (_Float16)M[k * HID + col];
  }
}

// x [T,N,32] fp32 -> fp16 pairs
__global__ __launch_bounds__(256) void xconv_kernel(const float* __restrict__ x,
                                                    __half2* __restrict__ xh) {
  size_t i = (size_t)blockIdx.x * 256 + threadIdx.x;
  if (i < XPAIRS) {
    float2 f = ((const float2*)x)[i];
    xh[i] = __floats2half2_rn(f.x, f.y);
  }
}

// bsort v4 (VALIDATED R30/R31/R33/R34): LDS-staged sort + sequential
// streamout at 512 threads. Coalesced reads, sequential writes: amp ~1.0.
__global__ __launch_bounds__(BST) void bsort_kernel(
    const int* __restrict__ ei, const float* __restrict__ ew,
    unsigned long long* __restrict__ bin2G, int* __restrict__ runoffG,
    int tbase) {
  __shared__ int hist[NB];
  __shared__ int rnk[NB];
  __shared__ int lbase[NB + 1];
  __shared__ unsigned long long sent[EPB];  // 64 KB sorted-entry buffer
  int tl = blockIdx.y;
  const int* src = ei + (size_t)(tbase + tl) * 2 * EE;
  const int* dst = src + EE;
  const float* w = ew + (size_t)(tbase + tl) * EE;
  int t = threadIdx.x;
  for (int i = t; i < NB; i += BST) { hist[i] = 0; rnk[i] = 0; }
  __syncthreads();
  int e0 = blockIdx.x * EPB;
  int cnt = min(EPB, EE - e0);
  for (int i = t; i < cnt; i += BST) atomicAdd(&hist[dst[e0 + i] >> 6], 1);
  __syncthreads();
  if (t == 0) {
    int run = 0;
    for (int b = 0; b < NB; ++b) { lbase[b] = run; run += hist[b]; }
    lbase[NB] = run;  // == cnt
  }
  __syncthreads();
  int* rof = runoffG + ((size_t)tl * ABLK + blockIdx.x) * (NB + 1);
  for (int b = t; b < NB + 1; b += BST) rof[b] = lbase[b];
  for (int i = t; i < cnt; i += BST) {
    int d = dst[e0 + i], s = src[e0 + i];
    int b = d >> 6;
    unsigned short hw = __half_as_ushort(__float2half_rn(w[e0 + i]));
    int pos = lbase[b] + atomicAdd(&rnk[b], 1);
    sent[pos] = (unsigned long long)((unsigned)s | ((unsigned)(d & 63) << 16)) |
                ((unsigned long long)hw << 32);
  }
  __syncthreads();
  unsigned long long* reg = bin2G + ((size_t)tl * ABLK + blockIdx.x) * EPB;
  for (int i = t; i < cnt; i += BST) reg[i] = sent[i];
}

// bscan v2 (VALIDATED R26): bucket totals from runoff diffs + 1024-wide scan.
__global__ __launch_bounds__(1024) void bscan_kernel(const int* __restrict__ runoffG,
                                                     int* __restrict__ bbaseA) {
  __shared__ int s[1024];
  int tl = blockIdx.x, t = threadIdx.x;
  const int* runoff = runoffG + (size_t)tl * ABLK * (NB + 1);
  int v = 0;
  if (t < NB) {
    for (int blk = 0; blk < ABLK; ++blk)
      v += runoff[blk * (NB + 1) + t + 1] - runoff[blk * (NB + 1) + t];
  }
  s[t] = v;
  __syncthreads();
  for (int o = 1; o < 1024; o <<= 1) {
    int u = (t >= o) ? s[t - o] : 0;
    __syncthreads();
    s[t] += u;
    __syncthreads();
  }
  if (t < NB) bbaseA[(size_t)tl * NB + t] = s[t] - v;  // exclusive
}

// sortdeg v3: R34-validated 16x16 merge + NEW: writes xs = dinv * xh rows
// for its own 64 nodes (coalesced 4 KB read + 4 KB write). This lets gather
// drop the per-edge dinv[src] lookup entirely (algebra: y[d] =
// dinv[d]*(sum w*xs[src] + xs[d]) with xs[n] = dinv[n]*x[n]).
__global__ __launch_bounds__(256) void sortdeg_kernel(
    const int* __restrict__ runoffG, const unsigned long long* __restrict__ bin2G,
    const int* __restrict__ bbaseA, float* __restrict__ dinvA,
    unsigned* __restrict__ sbufG, int* __restrict__ noffG,
    const __half2* __restrict__ xh, __half2* __restrict__ xs, int tbase) {
  __shared__ float wsum[BSZ];
  __shared__ int cnt[BSZ];
  __shared__ int plc[BSZ];
  __shared__ int loff[BSZ];
  int tl = blockIdx.y, b = blockIdx.x;
  int t = threadIdx.x;
  if (t < BSZ) { wsum[t] = 0.f; cnt[t] = 0; }
  __syncthreads();
  const int* runoff = runoffG + (size_t)tl * ABLK * (NB + 1);
  int g = t >> 4;      // lane-group 0..15
  int lane = t & 15;
  // pass 1: wsum + cnt over the bucket's runs
  for (int blk = g; blk < ABLK; blk += 16) {
    int r0 = runoff[blk * (NB + 1) + b];
    int r1 = runoff[blk * (NB + 1) + b + 1];
    const unsigned long long* reg = bin2G + ((size_t)tl * ABLK + blk) * EPB;
    for (int i = r0 + lane; i < r1; i += 16) {
      unsigned long long u = reg[i];
      int dl = (int)((u >> 16) & 63u);
      atomicAdd(&wsum[dl], __half2float(__ushort_as_half((unsigned short)(u >> 32))));
      atomicAdd(&cnt[dl], 1);
    }
  }
  __syncthreads();
  if (t == 0) {
    int run = 0;
#pragma unroll
    for (int i = 0; i < BSZ; ++i) { loff[i] = run; run += cnt[i]; }
  }
  __syncthreads();
  int base = bbaseA[(size_t)tl * NB + b];
  int* noff = noffG + (size_t)tl * (NN + 1);
  if (t < BSZ) {
    int n = b * BSZ + t;
    int v = base + loff[t];
    plc[t] = v;
    if (n < NN) {
      noff[n] = v;
      dinvA[(size_t)tl * NN + n] = rsqrtf(1.0f + wsum[t]);
    }
  }
  if (b == 0 && t == 0) noff[NN] = EE;
  // write xs rows for this bucket: thread covers node (t>>2), quad (t&3)
  {
    int nl = t >> 2;
    int q = t & 3;
    int n = b * BSZ + nl;
    if (n < NN) {
      float dv = rsqrtf(1.0f + wsum[nl]);
      const __half2* xhT = xh + (size_t)(tbase + tl) * NN * 16;
      __half2* xsT = xs + (size_t)(tbase + tl) * NN * 16;
      uint4 xv = ((const uint4*)(xhT + (size_t)n * 16))[q];
      const __half2* hp = (const __half2*)&xv;
      __half2 o[4];
#pragma unroll
      for (int i = 0; i < 4; ++i) {
        float2 f = __half22float2(hp[i]);
        o[i] = __floats2half2_rn(dv * f.x, dv * f.y);
      }
      ((uint4*)(xsT + (size_t)n * 16))[q] = *(const uint4*)o;
    }
  }
  __syncthreads();
  unsigned* sbuf = sbufG + (size_t)tl * EE;
  // pass 2: place {src16 | raw fp16 w << 16} (runs L1/L2-hot from pass 1)
  for (int blk = g; blk < ABLK; blk += 16) {
    int r0 = runoff[blk * (NB + 1) + b];
    int r1 = runoff[blk * (NB + 1) + b + 1];
    const unsigned long long* reg = bin2G + ((size_t)tl * ABLK + blk) * EPB;
    for (int i = r0 + lane; i < r1; i += 16) {
      unsigned long long u = reg[i];
      int pos = atomicAdd(&plc[(int)((u >> 16) & 63u)], 1);
      sbuf[pos] = (unsigned)(u & 0xFFFFu) | ((unsigned)(u >> 32) << 16);
    }
  }
}

// Pass B1 (R31/R33/R34 structure): pure gather over PRE-SCALED xs. Inner
// loop = sbuf unpack + row load + 8 FMA (dinv[src] lookup and w*dinv mul
// eliminated). Epilogue: y = dv * (v + xs[d]).
__global__ __launch_bounds__(256) void gather_y_kernel(
    const __half2* __restrict__ xs,
    const float* __restrict__ dinvA, const int* __restrict__ noffG,
    const unsigned* __restrict__ sbufG, __half2* __restrict__ yG, int tbase) {
  int t = threadIdx.x;
  int w = t >> 6;            // wave 0..3
  int lane = t & 63;
  int h2 = lane >> 5;        // node half 0/1
  int g = (lane >> 2) & 7;   // edge group 0..7
  int cq = lane & 3;         // channel oct 0..3 (8 fp16 ch = uint4)
  int tl = blockIdx.y;
  int n = blockIdx.x * 8 + w * 2 + h2;  // NN % 8 == 0, no tail

  const float* dinv = dinvA + (size_t)tl * NN;
  const int* noff = noffG + (size_t)tl * (NN + 1);
  const unsigned* sbuf = sbufG + (size_t)tl * EE;
  const __half2* xst = xs + (size_t)(tbase + tl) * NN * 16;

  int e0 = noff[n], e1 = noff[n + 1];
  float v0 = 0.f, v1 = 0.f, v2 = 0.f, v3 = 0.f;
  float v4 = 0.f, v5 = 0.f, v6 = 0.f, v7 = 0.f;
  for (int e = e0 + g; e < e1; e += 8) {
    unsigned u = sbuf[e];  // 4 lanes same addr: broadcast; intra-line reuse
    int s = (int)(u & 0xFFFFu);
    float nm = __half2float(__ushort_as_half((unsigned short)(u >> 16)));
    uint4 xr = ((const uint4*)(xst + (size_t)s * 16))[cq];
    const __half2* hp = (const __half2*)&xr;
    float2 f0 = __half22float2(hp[0]);
    float2 f1 = __half22float2(hp[1]);
    float2 f2 = __half22float2(hp[2]);
    float2 f3 = __half22float2(hp[3]);
    v0 += nm * f0.x; v1 += nm * f0.y;
    v2 += nm * f1.x; v3 += nm * f1.y;
    v4 += nm * f2.x; v5 += nm * f2.y;
    v6 += nm * f3.x; v7 += nm * f3.y;
  }
  // reduce over the 8 edge groups (lane bits 2,3,4 — stays in node half/oct)
#pragma unroll
  for (int m = 4; m <= 16; m <<= 1) {
    v0 += __shfl_xor(v0, m); v1 += __shfl_xor(v1, m);
    v2 += __shfl_xor(v2, m); v3 += __shfl_xor(v3, m);
    v4 += __shfl_xor(v4, m); v5 += __shfl_xor(v5, m);
    v6 += __shfl_xor(v6, m); v7 += __shfl_xor(v7, m);
  }
  if (g == 0) {  // 4 lanes per node x 8 ch = all 32 channels
    float dv = dinv[n];
    uint4 xsr = ((const uint4*)(xst + (size_t)n * 16))[cq];  // xs self term
    const __half2* hs = (const __half2*)&xsr;
    float2 s0 = __half22float2(hs[0]);
    float2 s1 = __half22float2(hs[1]);
    float2 s2 = __half22float2(hs[2]);
    float2 s3 = __half22float2(hs[3]);
    __half2 o[4];
    o[0] = __floats2half2_rn(dv * (v0 + s0.x), dv * (v1 + s0.y));
    o[1] = __floats2half2_rn(dv * (v2 + s1.x), dv * (v3 + s1.y));
    o[2] = __floats2half2_rn(dv * (v4 + s2.x), dv * (v5 + s2.y));
    o[3] = __floats2half2_rn(dv * (v6 + s3.x), dv * (v7 + s3.y));
    __half2* yp = yG + ((size_t)tl * NN + n) * 16 + cq * 4;
    *(uint4*)yp = *(const uint4*)o;  // 16B store; 4 lanes fill the 64B row
  }
}

// Pass B2: MFMA gate (proven R17..R34). P[64x64] = Y[64x32] @ M[32x64]
// per (64-node tile, t) via 16x16x32_f16; B-frags prepacked, loaded once.
__global__ __launch_bounds__(256) void gate_acc_kernel(
    const __half2* __restrict__ yG, const _Float16* __restrict__ B16,
    const float* __restrict__ Bz, const float* __restrict__ Bh,
    float* __restrict__ acc, int c) {
  int t = threadIdx.x;
  int w = t >> 6;
  int lane = t & 63;
  int nb = blockIdx.x * BSZ;
  int t0 = blockIdx.y * GT;
  int te = min(t0 + GT, c);

  half8_t bf[8];
#pragma unroll
  for (int q = 0; q < 8; ++q)
    bf[q] = *(const half8_t*)(B16 + ((size_t)q * 64 + lane) * 8);
  float bzv[4], bhv[4];
#pragma unroll
  for (int cc = 0; cc < 4; ++cc) {
    bzv[cc] = Bz[cc * 16 + (lane & 15)];
    bhv[cc] = Bh[cc * 16 + (lane & 15)];
  }
  float accr[16];
#pragma unroll
  for (int k = 0; k < 16; ++k) accr[k] = 0.f;

  const _Float16* yF = (const _Float16*)yG;
  int arow = nb + w * 16 + (lane & 15);   // A row this lane loads
  if (arow >= NN) arow = NN - 1;          // tail clamp (results discarded)
  int koff = (lane >> 4) * 8;             // k-offset within the row

  for (int tl = t0; tl < te; ++tl) {
    half8_t a = *(const half8_t*)(yF + ((size_t)tl * NN + arow) * 32 + koff);
    f32x4_t dz0 = {0.f, 0.f, 0.f, 0.f};
    f32x4_t dz[4], dh[4];
#pragma unroll
    for (int cc = 0; cc < 4; ++cc) {
      dz[cc] = __builtin_amdgcn_mfma_f32_16x16x32_f16(a, bf[cc], dz0, 0, 0, 0);
      dh[cc] = __builtin_amdgcn_mfma_f32_16x16x32_f16(a, bf[4 + cc], dz0, 0, 0, 0);
    }
#pragma unroll
    for (int cc = 0; cc < 4; ++cc) {
#pragma unroll
      for (int r = 0; r < 4; ++r) {
        float za = dz[cc][r] + bzv[cc];
        float ha = dh[cc][r] + bhv[cc];
        float z = 1.0f / (1.0f + __expf(-za));
        float th = 1.0f - 2.0f / (__expf(2.f * ha) + 1.0f);
        accr[cc * 4 + r] += (1.0f - z) * th;
      }
    }
  }
#pragma unroll
  for (int cc = 0; cc < 4; ++cc) {
#pragma unroll
    for (int r = 0; r < 4; ++r) {
      int n = nb + w * 16 + (lane >> 4) * 4 + r;
      int j = cc * 16 + (lane & 15);
      if (n < NN) atomicAdd(&acc[(size_t)n * HID + j], accr[cc * 4 + r]);
    }
  }
}

// out[n][o] = (acc[n]/T) . W_out[:,o] + b_out[o]
__global__ __launch_bounds__(256) void out_kernel(const float* __restrict__ acc,
                                                  const float* __restrict__ W_out,
                                                  const float* __restrict__ b_out,
                                                  float* __restrict__ out) {
  __shared__ float sW[HID * OUT_C], sB[OUT_C];
  for (int i = threadIdx.x; i < HID * OUT_C; i += 256) sW[i] = W_out[i];
  if (threadIdx.x < OUT_C) sB[threadIdx.x] = b_out[threadIdx.x];
  __syncthreads();
  unsigned tid = blockIdx.x * 256u + threadIdx.x;
  unsigned n = tid >> 5;
  int o = tid & 31;
  if (n >= NN) return;
  const float* ar = acc + (size_t)n * HID;
  float v = 0.f;
#pragma unroll
  for (int k = 0; k < HID; ++k) v += ar[k] * sW[k * OUT_C + o];
  out[(size_t)n * OUT_C + o] = v * (1.0f / (float)TT) + sB[o];
}

static inline char* alignp(char* p, size_t a) {
  return (char*)(((size_t)p + a - 1) & ~(a - 1));
}

extern "C" void kernel_launch(void* const* d_in, const int* in_sizes, int n_in,
                              void* d_out, int out_size, void* d_ws, size_t ws_size,
                              hipStream_t stream) {
  const float* x     = (const float*)d_in[0];  // [T,N,32]
  const int*   ei    = (const int*)d_in[1];    // [T,2,E]
  const float* ew    = (const float*)d_in[2];  // [T,E]
  const float* Wz    = (const float*)d_in[3];
  const float* bz    = (const float*)d_in[4];
  // d_in[5..6] (Wr,br) dead: H==0 so R unused
  const float* Wh    = (const float*)d_in[7];
  const float* bh    = (const float*)d_in[8];
  const float* Lz_w  = (const float*)d_in[9];
  const float* Lz_b  = (const float*)d_in[10];
  // d_in[11..12] (Lr) dead
  const float* Lh_w  = (const float*)d_in[13];
  const float* Lh_b  = (const float*)d_in[14];
  const float* W_out = (const float*)d_in[15];
  const float* b_out = (const float*)d_in[16];
  float* out = (float*)d_out;

  // per-t sizes (bytes)
  const size_t noffB  = (size_t)(NN + 1) * 4;
  const size_t dinvB  = (size_t)NN * 4;
  const size_t bbB    = (size_t)NB * 4;
  const size_t rofB   = (size_t)ABLK * (NB + 1) * 4;      // 307 KB
  const size_t sbufB  = (size_t)EE * 4;                   // 3.2 MB
  const size_t bin2B  = (size_t)ABLK * EPB * 8;           // 6.42 MB (y aliases)
  const size_t perT   = noffB + dinvB + bbB + rofB + sbufB + bin2B;
  const size_t xhB    = XPAIRS * 4;                       // 38.4 MB
  const size_t fixedB = 4 * ((size_t)2 * IN_C * HID + 2 * HID)
                      + 8192 + (size_t)NN * HID * 4 + 2 * xhB + 4096;  // ~90 MB

  int nt = 12;
  if (ws_size < fixedB + 12 * perT) {
    nt = (int)((ws_size - fixedB) / perT);
    if (nt < 1) nt = 1;
    if (nt > 12) nt = 12;
  }

  char* p = (char*)d_ws;
  unsigned long long* bin2 = (unsigned long long*)p;  // 8-aligned at base
  p += bin2B * nt;
  int* noffG  = (int*)p;          p += noffB * nt;
  float* dinv = (float*)p;        p += dinvB * nt;
  int* bbase  = (int*)p;          p += bbB * nt;
  int* runoff = (int*)p;          p += rofB * nt;
  unsigned* sbufG = (unsigned*)p; p += sbufB * nt;
  p = alignp(p, 16);
  _Float16* B16 = (_Float16*)p;   p += 8192;  // 4096 fp16 MFMA B-frags
  float* Mz = (float*)p;
  float* Mh = Mz + IN_C * HID;
  float* Bz = Mh + IN_C * HID;
  float* Bh = Bz + HID;
  float* acc = Bh + HID;  // [N,64]
  p = alignp((char*)(acc + (size_t)NN * HID), 256);
  __half2* xh = (__half2*)p;      p += xhB;
  __half2* xs = (__half2*)p;      p += xhB;   // dinv-pre-scaled x (fp16)
  // y [nt,N,32] fp16 aliases the bin2 region: bin2 is dead after sortdeg;
  // stream order guarantees sortdeg (reads bin2) < gather_y (writes y) <
  // gate_acc (reads y) < next chunk's bsort (rewrites bin2).
  __half2* yG = (__half2*)bin2;

  prep_kernel<<<dim3(IN_C + 1, 2), 64, 0, stream>>>(Wz, bz, Lz_w, Lz_b, Wh, bh,
                                                    Lh_w, Lh_b, Mz, Bz, Mh, Bh);
  prep_b16_kernel<<<dim3(4, 2), 64, 0, stream>>>(Mz, Mh, B16);
  xconv_kernel<<<(unsigned)((XPAIRS + 255) / 256), 256, 0, stream>>>(x, xh);
  hipMemsetAsync(acc, 0, (size_t)NN * HID * sizeof(float), stream);

  for (int tb = 0; tb < TT; tb += nt) {
    int c = (TT - tb < nt) ? (TT - tb) : nt;
    bsort_kernel<<<dim3(ABLK, c), BST, 0, stream>>>(ei, ew, bin2, runoff, tb);
    bscan_kernel<<<c, 1024, 0, stream>>>(runoff, bbase);
    sortdeg_kernel<<<dim3(NB, c), 256, 0, stream>>>(runoff, bin2, bbase,
                                                    dinv, sbufG, noffG,
                                                    xh, xs, tb);
    gather_y_kernel<<<dim3(NN / 8, c), 256, 0, stream>>>(xs, dinv, noffG,
                                                         sbufG, yG, tb);
    gate_acc_kernel<<<dim3(NB, (c + GT - 1) / GT), 256, 0, stream>>>(
        yG, B16, Bz, Bh, acc, c);
  }

  out_kernel<<<(NN * OUT_C + 255) / 256, 256, 0, stream>>>(acc, W_out, b_out, out);
}

// Round 36
// 453.376 us; speedup vs baseline: 1.1717x; 1.0350x over previous
//
#include <hip/hip_runtime.h>
#include <hip/hip_fp16.h>

#define NN 50000
#define TT 12
#define EE 800000
#define IN_C 32
#define HID 64
#define OUT_C 32
#define BSZ 64                        // nodes per bucket
#define NB ((NN + BSZ - 1) / BSZ)     // 782 buckets
#define EPB 8192                      // edges per bsort block (ent fits LDS)
#define ABLK ((EE + EPB - 1) / EPB)   // 98
#define BST 512                       // bsort threads (8 waves: occupancy)
#define GT 4                          // timesteps per gate block
#define XPAIRS ((size_t)TT * NN * 16) // half2 elements in x

typedef _Float16 half8_t __attribute__((ext_vector_type(8)));
typedef float f32x4_t __attribute__((ext_vector_type(4)));

// ---------------- precompute folded gate matrices ----------------
// Mz = Wz @ Lz_w[:64] (32x64), Bz = bz @ Lz_w[:64] + Lz_b (64); same for h.
__global__ __launch_bounds__(64) void prep_kernel(
    const float* __restrict__ Wz, const float* __restrict__ bz,
    const float* __restrict__ Lzw, const float* __restrict__ Lzb,
    const float* __restrict__ Wh, const float* __restrict__ bh,
    const float* __restrict__ Lhw, const float* __restrict__ Lhb,
    float* __restrict__ Mz, float* __restrict__ Bz,
    float* __restrict__ Mh, float* __restrict__ Bh) {
  const int j = threadIdx.x;
  const int i = blockIdx.x;
  const int h = blockIdx.y;
  const float* W  = h ? Wh  : Wz;
  const float* b  = h ? bh  : bz;
  const float* L  = h ? Lhw : Lzw;
  const float* Lb = h ? Lhb : Lzb;
  float* M = h ? Mh : Mz;
  float* B = h ? Bh : Bz;
  if (i < IN_C) {
    float v = 0.f;
    for (int k = 0; k < HID; ++k) v += W[i * HID + k] * L[k * HID + j];
    M[i * HID + j] = v;
  } else {
    float v = Lb[j];
    for (int k = 0; k < HID; ++k) v += b[k] * L[k * HID + j];
    B[j] = v;
  }
}

// pack M into MFMA B-operand fp16 layout: B16[(g*4+cc)*64 + lane][i] =
// M_g[k = 8*(lane>>4)+i][col = cc*16 + (lane&15)]
__global__ __launch_bounds__(64) void prep_b16_kernel(
    const float* __restrict__ Mz, const float* __restrict__ Mh,
    _Float16* __restrict__ B16) {
  int l = threadIdx.x;
  int cc = blockIdx.x;  // coltile 0..3
  int g = blockIdx.y;   // 0=z, 1=h
  const float* M = g ? Mh : Mz;
#pragma unroll
  for (int i = 0; i < 8; ++i) {
    int k = (l >> 4) * 8 + i;
    int col = cc * 16 + (l & 15);
    B16[(((size_t)g * 4 + cc) * 64 + l) * 8 + i] = (_Float16)M[k * HID + col];
  }
}

// x [T,N,32] fp32 -> fp16 pairs
__global__ __launch_bounds__(256) void xconv_kernel(const float* __restrict__ x,
                                                    __half2* __restrict__ xh) {
  size_t i = (size_t)blockIdx.x * 256 + threadIdx.x;
  if (i < XPAIRS) {
    float2 f = ((const float2*)x)[i];
    xh[i] = __floats2half2_rn(f.x, f.y);
  }
}

// bsort v4 (VALIDATED R30..R35): LDS-staged sort + sequential streamout at
// 512 threads. Coalesced reads, sequential writes: amp ~1.0 both sides.
__global__ __launch_bounds__(BST) void bsort_kernel(
    const int* __restrict__ ei, const float* __restrict__ ew,
    unsigned long long* __restrict__ bin2G, int* __restrict__ runoffG,
    int tbase) {
  __shared__ int hist[NB];
  __shared__ int rnk[NB];
  __shared__ int lbase[NB + 1];
  __shared__ unsigned long long sent[EPB];  // 64 KB sorted-entry buffer
  int tl = blockIdx.y;
  const int* src = ei + (size_t)(tbase + tl) * 2 * EE;
  const int* dst = src + EE;
  const float* w = ew + (size_t)(tbase + tl) * EE;
  int t = threadIdx.x;
  for (int i = t; i < NB; i += BST) { hist[i] = 0; rnk[i] = 0; }
  __syncthreads();
  int e0 = blockIdx.x * EPB;
  int cnt = min(EPB, EE - e0);
  for (int i = t; i < cnt; i += BST) atomicAdd(&hist[dst[e0 + i] >> 6], 1);
  __syncthreads();
  if (t == 0) {
    int run = 0;
    for (int b = 0; b < NB; ++b) { lbase[b] = run; run += hist[b]; }
    lbase[NB] = run;  // == cnt
  }
  __syncthreads();
  int* rof = runoffG + ((size_t)tl * ABLK + blockIdx.x) * (NB + 1);
  for (int b = t; b < NB + 1; b += BST) rof[b] = lbase[b];
  for (int i = t; i < cnt; i += BST) {
    int d = dst[e0 + i], s = src[e0 + i];
    int b = d >> 6;
    unsigned short hw = __half_as_ushort(__float2half_rn(w[e0 + i]));
    int pos = lbase[b] + atomicAdd(&rnk[b], 1);
    sent[pos] = (unsigned long long)((unsigned)s | ((unsigned)(d & 63) << 16)) |
                ((unsigned long long)hw << 32);
  }
  __syncthreads();
  unsigned long long* reg = bin2G + ((size_t)tl * ABLK + blockIdx.x) * EPB;
  for (int i = t; i < cnt; i += BST) reg[i] = sent[i];
}

// bscan v2 (VALIDATED R26): bucket totals from runoff diffs + 1024-wide scan.
__global__ __launch_bounds__(1024) void bscan_kernel(const int* __restrict__ runoffG,
                                                     int* __restrict__ bbaseA) {
  __shared__ int s[1024];
  int tl = blockIdx.x, t = threadIdx.x;
  const int* runoff = runoffG + (size_t)tl * ABLK * (NB + 1);
  int v = 0;
  if (t < NB) {
    for (int blk = 0; blk < ABLK; ++blk)
      v += runoff[blk * (NB + 1) + t + 1] - runoff[blk * (NB + 1) + t];
  }
  s[t] = v;
  __syncthreads();
  for (int o = 1; o < 1024; o <<= 1) {
    int u = (t >= o) ? s[t - o] : 0;
    __syncthreads();
    s[t] += u;
    __syncthreads();
  }
  if (t < NB) bbaseA[(size_t)tl * NB + t] = s[t] - v;  // exclusive
}

// sortdeg v3 (VALIDATED R35): 16x16 merge + xs = dinv * xh row write.
__global__ __launch_bounds__(256) void sortdeg_kernel(
    const int* __restrict__ runoffG, const unsigned long long* __restrict__ bin2G,
    const int* __restrict__ bbaseA, float* __restrict__ dinvA,
    unsigned* __restrict__ sbufG, int* __restrict__ noffG,
    const __half2* __restrict__ xh, __half2* __restrict__ xs, int tbase) {
  __shared__ float wsum[BSZ];
  __shared__ int cnt[BSZ];
  __shared__ int plc[BSZ];
  __shared__ int loff[BSZ];
  int tl = blockIdx.y, b = blockIdx.x;
  int t = threadIdx.x;
  if (t < BSZ) { wsum[t] = 0.f; cnt[t] = 0; }
  __syncthreads();
  const int* runoff = runoffG + (size_t)tl * ABLK * (NB + 1);
  int g = t >> 4;      // lane-group 0..15
  int lane = t & 15;
  // pass 1: wsum + cnt over the bucket's runs
  for (int blk = g; blk < ABLK; blk += 16) {
    int r0 = runoff[blk * (NB + 1) + b];
    int r1 = runoff[blk * (NB + 1) + b + 1];
    const unsigned long long* reg = bin2G + ((size_t)tl * ABLK + blk) * EPB;
    for (int i = r0 + lane; i < r1; i += 16) {
      unsigned long long u = reg[i];
      int dl = (int)((u >> 16) & 63u);
      atomicAdd(&wsum[dl], __half2float(__ushort_as_half((unsigned short)(u >> 32))));
      atomicAdd(&cnt[dl], 1);
    }
  }
  __syncthreads();
  if (t == 0) {
    int run = 0;
#pragma unroll
    for (int i = 0; i < BSZ; ++i) { loff[i] = run; run += cnt[i]; }
  }
  __syncthreads();
  int base = bbaseA[(size_t)tl * NB + b];
  int* noff = noffG + (size_t)tl * (NN + 1);
  if (t < BSZ) {
    int n = b * BSZ + t;
    int v = base + loff[t];
    plc[t] = v;
    if (n < NN) {
      noff[n] = v;
      dinvA[(size_t)tl * NN + n] = rsqrtf(1.0f + wsum[t]);
    }
  }
  if (b == 0 && t == 0) noff[NN] = EE;
  // write xs rows for this bucket: thread covers node (t>>2), quad (t&3)
  {
    int nl = t >> 2;
    int q = t & 3;
    int n = b * BSZ + nl;
    if (n < NN) {
      float dv = rsqrtf(1.0f + wsum[nl]);
      const __half2* xhT = xh + (size_t)(tbase + tl) * NN * 16;
      __half2* xsT = xs + (size_t)(tbase + tl) * NN * 16;
      uint4 xv = ((const uint4*)(xhT + (size_t)n * 16))[q];
      const __half2* hp = (const __half2*)&xv;
      __half2 o[4];
#pragma unroll
      for (int i = 0; i < 4; ++i) {
        float2 f = __half22float2(hp[i]);
        o[i] = __floats2half2_rn(dv * f.x, dv * f.y);
      }
      ((uint4*)(xsT + (size_t)n * 16))[q] = *(const uint4*)o;
    }
  }
  __syncthreads();
  unsigned* sbuf = sbufG + (size_t)tl * EE;
  // pass 2: place {src16 | raw fp16 w << 16} (runs L1/L2-hot from pass 1)
  for (int blk = g; blk < ABLK; blk += 16) {
    int r0 = runoff[blk * (NB + 1) + b];
    int r1 = runoff[blk * (NB + 1) + b + 1];
    const unsigned long long* reg = bin2G + ((size_t)tl * ABLK + blk) * EPB;
    for (int i = r0 + lane; i < r1; i += 16) {
      unsigned long long u = reg[i];
      int pos = atomicAdd(&plc[(int)((u >> 16) & 63u)], 1);
      sbuf[pos] = (unsigned)(u & 0xFFFFu) | ((unsigned)(u >> 32) << 16);
    }
  }
}

// Pass B1 (R35 structure + 2-deep branchless unroll): pure gather over
// pre-scaled xs. Two edges (stride 8) per iteration: both sbuf loads issue
// together, then both xs row loads — doubling MLP on the dependent chain
// (R35: 53% VALU, chain walked ~2x serially). The out-of-range second slot
// substitutes u=0 -> s=0, nm=fp16(0)=0 -> contributes exactly 0 (branchless).
__global__ __launch_bounds__(256) void gather_y_kernel(
    const __half2* __restrict__ xs,
    const float* __restrict__ dinvA, const int* __restrict__ noffG,
    const unsigned* __restrict__ sbufG, __half2* __restrict__ yG, int tbase) {
  int t = threadIdx.x;
  int w = t >> 6;            // wave 0..3
  int lane = t & 63;
  int h2 = lane >> 5;        // node half 0/1
  int g = (lane >> 2) & 7;   // edge group 0..7
  int cq = lane & 3;         // channel oct 0..3 (8 fp16 ch = uint4)
  int tl = blockIdx.y;
  int n = blockIdx.x * 8 + w * 2 + h2;  // NN % 8 == 0, no tail

  const float* dinv = dinvA + (size_t)tl * NN;
  const int* noff = noffG + (size_t)tl * (NN + 1);
  const unsigned* sbuf = sbufG + (size_t)tl * EE;
  const __half2* xst = xs + (size_t)(tbase + tl) * NN * 16;

  int e0 = noff[n], e1 = noff[n + 1];
  float v0 = 0.f, v1 = 0.f, v2 = 0.f, v3 = 0.f;
  float v4 = 0.f, v5 = 0.f, v6 = 0.f, v7 = 0.f;
  for (int e = e0 + g; e < e1; e += 16) {
    unsigned uA = sbuf[e];
    int eB = e + 8;
    unsigned uB = (eB < e1) ? sbuf[eB] : 0u;  // 0 -> nm=0: contributes 0
    int sA = (int)(uA & 0xFFFFu);
    int sB = (int)(uB & 0xFFFFu);
    float nmA = __half2float(__ushort_as_half((unsigned short)(uA >> 16)));
    float nmB = __half2float(__ushort_as_half((unsigned short)(uB >> 16)));
    uint4 xrA = ((const uint4*)(xst + (size_t)sA * 16))[cq];
    uint4 xrB = ((const uint4*)(xst + (size_t)sB * 16))[cq];
    const __half2* hA = (const __half2*)&xrA;
    const __half2* hB = (const __half2*)&xrB;
    float2 a0 = __half22float2(hA[0]);
    float2 a1 = __half22float2(hA[1]);
    float2 a2 = __half22float2(hA[2]);
    float2 a3 = __half22float2(hA[3]);
    v0 += nmA * a0.x; v1 += nmA * a0.y;
    v2 += nmA * a1.x; v3 += nmA * a1.y;
    v4 += nmA * a2.x; v5 += nmA * a2.y;
    v6 += nmA * a3.x; v7 += nmA * a3.y;
    float2 b0 = __half22float2(hB[0]);
    float2 b1 = __half22float2(hB[1]);
    float2 b2 = __half22float2(hB[2]);
    float2 b3 = __half22float2(hB[3]);
    v0 += nmB * b0.x; v1 += nmB * b0.y;
    v2 += nmB * b1.x; v3 += nmB * b1.y;
    v4 += nmB * b2.x; v5 += nmB * b2.y;
    v6 += nmB * b3.x; v7 += nmB * b3.y;
  }
  // reduce over the 8 edge groups (lane bits 2,3,4 — stays in node half/oct)
#pragma unroll
  for (int m = 4; m <= 16; m <<= 1) {
    v0 += __shfl_xor(v0, m); v1 += __shfl_xor(v1, m);
    v2 += __shfl_xor(v2, m); v3 += __shfl_xor(v3, m);
    v4 += __shfl_xor(v4, m); v5 += __shfl_xor(v5, m);
    v6 += __shfl_xor(v6, m); v7 += __shfl_xor(v7, m);
  }
  if (g == 0) {  // 4 lanes per node x 8 ch = all 32 channels
    float dv = dinv[n];
    uint4 xsr = ((const uint4*)(xst + (size_t)n * 16))[cq];  // xs self term
    const __half2* hs = (const __half2*)&xsr;
    float2 s0 = __half22float2(hs[0]);
    float2 s1 = __half22float2(hs[1]);
    float2 s2 = __half22float2(hs[2]);
    float2 s3 = __half22float2(hs[3]);
    __half2 o[4];
    o[0] = __floats2half2_rn(dv * (v0 + s0.x), dv * (v1 + s0.y));
    o[1] = __floats2half2_rn(dv * (v2 + s1.x), dv * (v3 + s1.y));
    o[2] = __floats2half2_rn(dv * (v4 + s2.x), dv * (v5 + s2.y));
    o[3] = __floats2half2_rn(dv * (v6 + s3.x), dv * (v7 + s3.y));
    __half2* yp = yG + ((size_t)tl * NN + n) * 16 + cq * 4;
    *(uint4*)yp = *(const uint4*)o;  // 16B store; 4 lanes fill the 64B row
  }
}

// Pass B2: MFMA gate (proven R17..R35). P[64x64] = Y[64x32] @ M[32x64]
// per (64-node tile, t) via 16x16x32_f16; B-frags prepacked, loaded once.
__global__ __launch_bounds__(256) void gate_acc_kernel(
    const __half2* __restrict__ yG, const _Float16* __restrict__ B16,
    const float* __restrict__ Bz, const float* __restrict__ Bh,
    float* __restrict__ acc, int c) {
  int t = threadIdx.x;
  int w = t >> 6;
  int lane = t & 63;
  int nb = blockIdx.x * BSZ;
  int t0 = blockIdx.y * GT;
  int te = min(t0 + GT, c);

  half8_t bf[8];
#pragma unroll
  for (int q = 0; q < 8; ++q)
    bf[q] = *(const half8_t*)(B16 + ((size_t)q * 64 + lane) * 8);
  float bzv[4], bhv[4];
#pragma unroll
  for (int cc = 0; cc < 4; ++cc) {
    bzv[cc] = Bz[cc * 16 + (lane & 15)];
    bhv[cc] = Bh[cc * 16 + (lane & 15)];
  }
  float accr[16];
#pragma unroll
  for (int k = 0; k < 16; ++k) accr[k] = 0.f;

  const _Float16* yF = (const _Float16*)yG;
  int arow = nb + w * 16 + (lane & 15);   // A row this lane loads
  if (arow >= NN) arow = NN - 1;          // tail clamp (results discarded)
  int koff = (lane >> 4) * 8;             // k-offset within the row

  for (int tl = t0; tl < te; ++tl) {
    half8_t a = *(const half8_t*)(yF + ((size_t)tl * NN + arow) * 32 + koff);
    f32x4_t dz0 = {0.f, 0.f, 0.f, 0.f};
    f32x4_t dz[4], dh[4];
#pragma unroll
    for (int cc = 0; cc < 4; ++cc) {
      dz[cc] = __builtin_amdgcn_mfma_f32_16x16x32_f16(a, bf[cc], dz0, 0, 0, 0);
      dh[cc] = __builtin_amdgcn_mfma_f32_16x16x32_f16(a, bf[4 + cc], dz0, 0, 0, 0);
    }
#pragma unroll
    for (int cc = 0; cc < 4; ++cc) {
#pragma unroll
      for (int r = 0; r < 4; ++r) {
        float za = dz[cc][r] + bzv[cc];
        float ha = dh[cc][r] + bhv[cc];
        float z = 1.0f / (1.0f + __expf(-za));
        float th = 1.0f - 2.0f / (__expf(2.f * ha) + 1.0f);
        accr[cc * 4 + r] += (1.0f - z) * th;
      }
    }
  }
#pragma unroll
  for (int cc = 0; cc < 4; ++cc) {
#pragma unroll
    for (int r = 0; r < 4; ++r) {
      int n = nb + w * 16 + (lane >> 4) * 4 + r;
      int j = cc * 16 + (lane & 15);
      if (n < NN) atomicAdd(&acc[(size_t)n * HID + j], accr[cc * 4 + r]);
    }
  }
}

// out[n][o] = (acc[n]/T) . W_out[:,o] + b_out[o]
__global__ __launch_bounds__(256) void out_kernel(const float* __restrict__ acc,
                                                  const float* __restrict__ W_out,
                                                  const float* __restrict__ b_out,
                                                  float* __restrict__ out) {
  __shared__ float sW[HID * OUT_C], sB[OUT_C];
  for (int i = threadIdx.x; i < HID * OUT_C; i += 256) sW[i] = W_out[i];
  if (threadIdx.x < OUT_C) sB[threadIdx.x] = b_out[threadIdx.x];
  __syncthreads();
  unsigned tid = blockIdx.x * 256u + threadIdx.x;
  unsigned n = tid >> 5;
  int o = tid & 31;
  if (n >= NN) return;
  const float* ar = acc + (size_t)n * HID;
  float v = 0.f;
#pragma unroll
  for (int k = 0; k < HID; ++k) v += ar[k] * sW[k * OUT_C + o];
  out[(size_t)n * OUT_C + o] = v * (1.0f / (float)TT) + sB[o];
}

static inline char* alignp(char* p, size_t a) {
  return (char*)(((size_t)p + a - 1) & ~(a - 1));
}

extern "C" void kernel_launch(void* const* d_in, const int* in_sizes, int n_in,
                              void* d_out, int out_size, void* d_ws, size_t ws_size,
                              hipStream_t stream) {
  const float* x     = (const float*)d_in[0];  // [T,N,32]
  const int*   ei    = (const int*)d_in[1];    // [T,2,E]
  const float* ew    = (const float*)d_in[2];  // [T,E]
  const float* Wz    = (const float*)d_in[3];
  const float* bz    = (const float*)d_in[4];
  // d_in[5..6] (Wr,br) dead: H==0 so R unused
  const float* Wh    = (const float*)d_in[7];
  const float* bh    = (const float*)d_in[8];
  const float* Lz_w  = (const float*)d_in[9];
  const float* Lz_b  = (const float*)d_in[10];
  // d_in[11..12] (Lr) dead
  const float* Lh_w  = (const float*)d_in[13];
  const float* Lh_b  = (const float*)d_in[14];
  const float* W_out = (const float*)d_in[15];
  const float* b_out = (const float*)d_in[16];
  float* out = (float*)d_out;

  // per-t sizes (bytes)
  const size_t noffB  = (size_t)(NN + 1) * 4;
  const size_t dinvB  = (size_t)NN * 4;
  const size_t bbB    = (size_t)NB * 4;
  const size_t rofB   = (size_t)ABLK * (NB + 1) * 4;      // 307 KB
  const size_t sbufB  = (size_t)EE * 4;                   // 3.2 MB
  const size_t bin2B  = (size_t)ABLK * EPB * 8;           // 6.42 MB (y aliases)
  const size_t perT   = noffB + dinvB + bbB + rofB + sbufB + bin2B;
  const size_t xhB    = XPAIRS * 4;                       // 38.4 MB
  const size_t fixedB = 4 * ((size_t)2 * IN_C * HID + 2 * HID)
                      + 8192 + (size_t)NN * HID * 4 + 2 * xhB + 4096;  // ~90 MB

  int nt = 12;
  if (ws_size < fixedB + 12 * perT) {
    nt = (int)((ws_size - fixedB) / perT);
    if (nt < 1) nt = 1;
    if (nt > 12) nt = 12;
  }

  char* p = (char*)d_ws;
  unsigned long long* bin2 = (unsigned long long*)p;  // 8-aligned at base
  p += bin2B * nt;
  int* noffG  = (int*)p;          p += noffB * nt;
  float* dinv = (float*)p;        p += dinvB * nt;
  int* bbase  = (int*)p;          p += bbB * nt;
  int* runoff = (int*)p;          p += rofB * nt;
  unsigned* sbufG = (unsigned*)p; p += sbufB * nt;
  p = alignp(p, 16);
  _Float16* B16 = (_Float16*)p;   p += 8192;  // 4096 fp16 MFMA B-frags
  float* Mz = (float*)p;
  float* Mh = Mz + IN_C * HID;
  float* Bz = Mh + IN_C * HID;
  float* Bh = Bz + HID;
  float* acc = Bh + HID;  // [N,64]
  p = alignp((char*)(acc + (size_t)NN * HID), 256);
  __half2* xh = (__half2*)p;      p += xhB;
  __half2* xs = (__half2*)p;      p += xhB;   // dinv-pre-scaled x (fp16)
  // y [nt,N,32] fp16 aliases the bin2 region: bin2 is dead after sortdeg;
  // stream order guarantees sortdeg (reads bin2) < gather_y (writes y) <
  // gate_acc (reads y) < next chunk's bsort (rewrites bin2).
  __half2* yG = (__half2*)bin2;

  prep_kernel<<<dim3(IN_C + 1, 2), 64, 0, stream>>>(Wz, bz, Lz_w, Lz_b, Wh, bh,
                                                    Lh_w, Lh_b, Mz, Bz, Mh, Bh);
  prep_b16_kernel<<<dim3(4, 2), 64, 0, stream>>>(Mz, Mh, B16);
  xconv_kernel<<<(unsigned)((XPAIRS + 255) / 256), 256, 0, stream>>>(x, xh);
  hipMemsetAsync(acc, 0, (size_t)NN * HID * sizeof(float), stream);

  for (int tb = 0; tb < TT; tb += nt) {
    int c = (TT - tb < nt) ? (TT - tb) : nt;
    bsort_kernel<<<dim3(ABLK, c), BST, 0, stream>>>(ei, ew, bin2, runoff, tb);
    bscan_kernel<<<c, 1024, 0, stream>>>(runoff, bbase);
    sortdeg_kernel<<<dim3(NB, c), 256, 0, stream>>>(runoff, bin2, bbase,
                                                    dinv, sbufG, noffG,
                                                    xh, xs, tb);
    gather_y_kernel<<<dim3(NN / 8, c), 256, 0, stream>>>(xs, dinv, noffG,
                                                         sbufG, yG, tb);
    gate_acc_kernel<<<dim3(NB, (c + GT - 1) / GT), 256, 0, stream>>>(
        yG, B16, Bz, Bh, acc, c);
  }

  out_kernel<<<(NN * OUT_C + 255) / 256, 256, 0, stream>>>(acc, W_out, b_out, out);
}